// Round 1
// baseline (579.288 us; speedup 1.0000x reference)
//
#include <hip/hip_runtime.h>
#include <math.h>

#define N_NODES 16384
#define N_EDGES 262144
#define IN_DIM  512
#define HID     256
#define HEADS   4
#define NBATCH  64
#define ACTIONS 32
#define NEG_SLOPE 0.2f

__device__ __forceinline__ float lrelu(float v) { return v > 0.f ? v : NEG_SLOPE * v; }

// ---------------------------------------------------------------- utility
__global__ void zero_int_kernel(int* __restrict__ p, int n) {
    int i = blockIdx.x * 256 + threadIdx.x;
    if (i < n) p[i] = 0;
}

// Pack [W_l | W_r] into one [512, 512] row-major matrix.
__global__ void pack_wlr_kernel(const float* __restrict__ wl, const float* __restrict__ wr,
                                float* __restrict__ wlr) {
    int idx = blockIdx.x * 256 + threadIdx.x;   // 0 .. 512*512-1
    int k = idx >> 9;         // row (0..511)
    int j = idx & 511;        // col (0..511)
    wlr[idx] = (j < HID) ? wl[k * HID + j] : wr[k * HID + (j - HID)];
}

// Wstack[h*256+k][c] = gat_w[k][h*256+c]   (so T @ Wstack == sum_h tmp_h @ W_h)
__global__ void pack_wstack_kernel(const float* __restrict__ gat_w, float* __restrict__ ws) {
    int idx = blockIdx.x * 256 + threadIdx.x;   // 0 .. 1024*256-1
    int r = idx >> 8;          // 0..1023  (= h*256 + k)
    int c = idx & 255;         // 0..255
    int h = r >> 8;            // 0..3
    int k = r & 255;           // 0..255
    ws[idx] = gat_w[(size_t)k * (HEADS * HID) + h * HID + c];
}

// watt[j][c], j in 0..7: j<4 -> W_h @ att_src_h ; j>=4 -> W_h @ att_dst_h  (transposed layout [8][256])
__global__ void watt_kernel(const float* __restrict__ gat_w,
                            const float* __restrict__ att_src,
                            const float* __restrict__ att_dst,
                            float* __restrict__ watt) {
    int j = blockIdx.x;        // 0..7
    int c = threadIdx.x;       // 0..255 (plays the role of k)
    int hh = j & 3;
    const float* att = (j < 4) ? (att_src + hh * HID) : (att_dst + hh * HID);
    float s = 0.f;
    for (int cc = 0; cc < HID; cc++)
        s += gat_w[(size_t)c * (HEADS * HID) + hh * HID + cc] * att[cc];
    watt[j * HID + c] = s;
}

// ---------------------------------------------------------------- CSR build
__global__ void deg_kernel(const int* __restrict__ ei, int* __restrict__ deg) {
    int e = blockIdx.x * 256 + threadIdx.x;
    if (e < N_EDGES) atomicAdd(&deg[ei[N_EDGES + e]], 1);
}

__global__ void scan_kernel(const int* __restrict__ deg, int* __restrict__ row_start,
                            int* __restrict__ pos) {
    __shared__ int part[256];
    int t = threadIdx.x;
    int base = t * 64;
    int s = 0;
    for (int i = 0; i < 64; i++) s += deg[base + i];
    part[t] = s;
    __syncthreads();
    if (t == 0) {
        int acc = 0;
        for (int i = 0; i < 256; i++) { int v = part[i]; part[i] = acc; acc += v; }
    }
    __syncthreads();
    int run = part[t];
    for (int i = 0; i < 64; i++) {
        row_start[base + i] = run;
        pos[base + i] = run;
        run += deg[base + i];
    }
    if (t == 255) row_start[N_NODES] = run;
}

__global__ void fill_kernel(const int* __restrict__ ei, int* __restrict__ pos,
                            int* __restrict__ col) {
    int e = blockIdx.x * 256 + threadIdx.x;
    if (e < N_EDGES) {
        int s = ei[e];
        int d = ei[N_EDGES + e];
        int p = atomicAdd(&pos[d], 1);
        col[p] = s;
    }
}

// ---------------------------------------------------------------- SGEMM (fp32, 128x128x8, 8x8/thread)
// mode 0: C = A@B
// mode 1: C = relu(A@B * scale + bias[col])
__global__ __launch_bounds__(256) void sgemm_kernel(const float* __restrict__ A,
                                                    const float* __restrict__ B,
                                                    float* __restrict__ C,
                                                    int M, int Nn, int K,
                                                    const float* __restrict__ bias,
                                                    float scale, int mode) {
    __shared__ float As[8][128];
    __shared__ float Bs[8][128];
    int tid = threadIdx.x;
    int bx = blockIdx.x, by = blockIdx.y;

    int arow = tid >> 1;            // 0..127
    int acol = (tid & 1) * 4;       // 0 or 4
    int brow = tid >> 5;            // 0..7
    int bcol = (tid & 31) * 4;      // 0..124

    const float* Ab = A + (size_t)(by * 128 + arow) * K + acol;
    const float* Bb = B + (size_t)brow * Nn + bx * 128 + bcol;

    float acc[8][8] = {{0.f}};
    int row0 = (tid >> 4) * 8;
    int col0 = (tid & 15) * 8;

    for (int kt = 0; kt < K; kt += 8) {
        float4 av = *(const float4*)(Ab + kt);
        As[acol + 0][arow] = av.x;
        As[acol + 1][arow] = av.y;
        As[acol + 2][arow] = av.z;
        As[acol + 3][arow] = av.w;
        *(float4*)&Bs[brow][bcol] = *(const float4*)(Bb + (size_t)kt * Nn);
        __syncthreads();
#pragma unroll
        for (int k = 0; k < 8; k++) {
            float4 a0 = *(float4*)&As[k][row0];
            float4 a1 = *(float4*)&As[k][row0 + 4];
            float4 b0 = *(float4*)&Bs[k][col0];
            float4 b1 = *(float4*)&Bs[k][col0 + 4];
            float ar[8] = {a0.x, a0.y, a0.z, a0.w, a1.x, a1.y, a1.z, a1.w};
            float br[8] = {b0.x, b0.y, b0.z, b0.w, b1.x, b1.y, b1.z, b1.w};
#pragma unroll
            for (int i = 0; i < 8; i++)
#pragma unroll
                for (int j = 0; j < 8; j++) acc[i][j] = fmaf(ar[i], br[j], acc[i][j]);
        }
        __syncthreads();
    }

#pragma unroll
    for (int i = 0; i < 8; i++) {
        size_t off = (size_t)(by * 128 + row0 + i) * Nn + bx * 128 + col0;
        float out[8];
#pragma unroll
        for (int j = 0; j < 8; j++) {
            float v = acc[i][j];
            if (mode == 1) v = fmaxf(v * scale + bias[bx * 128 + col0 + j], 0.f);
            out[j] = v;
        }
        *(float4*)(C + off)     = make_float4(out[0], out[1], out[2], out[3]);
        *(float4*)(C + off + 4) = make_float4(out[4], out[5], out[6], out[7]);
    }
}

// ---------------------------------------------------------------- SAGE aggregation + h + attention scalars
// xlr[n] = [x@W_l (256) | x@W_r (256)]; h = relu(mean_nbr_proj + b_l + xr); a_att[n][0:8] = h[n]·watt[j]
__global__ __launch_bounds__(256) void sage_agg_kernel(const float* __restrict__ xlr,
                                                       const int* __restrict__ row_start,
                                                       const int* __restrict__ col,
                                                       const float* __restrict__ b_l,
                                                       const float* __restrict__ watt,
                                                       float* __restrict__ h,
                                                       float* __restrict__ a_att) {
    __shared__ float watt_s[8 * HID];
    for (int i = threadIdx.x; i < 8 * HID; i += 256) watt_s[i] = watt[i];
    __syncthreads();

    int wave = threadIdx.x >> 6;
    int lane = threadIdx.x & 63;
    int n = blockIdx.x * 4 + wave;
    int start = row_start[n], end = row_start[n + 1];
    int c0 = lane * 4;

    float4 acc = make_float4(0.f, 0.f, 0.f, 0.f);
    for (int e = start; e < end; e++) {
        int s = col[e];
        float4 v = *(const float4*)(xlr + (size_t)s * IN_DIM + c0);
        acc.x += v.x; acc.y += v.y; acc.z += v.z; acc.w += v.w;
    }
    float inv = 1.f / (float)max(end - start, 1);
    float4 xr = *(const float4*)(xlr + (size_t)n * IN_DIM + HID + c0);
    float4 bl = *(const float4*)(b_l + c0);
    float4 hv;
    hv.x = fmaxf(fmaf(acc.x, inv, bl.x + xr.x), 0.f);
    hv.y = fmaxf(fmaf(acc.y, inv, bl.y + xr.y), 0.f);
    hv.z = fmaxf(fmaf(acc.z, inv, bl.z + xr.z), 0.f);
    hv.w = fmaxf(fmaf(acc.w, inv, bl.w + xr.w), 0.f);
    *(float4*)(h + (size_t)n * HID + c0) = hv;

    float p[8];
#pragma unroll
    for (int j = 0; j < 8; j++) {
        float4 wt = *(const float4*)&watt_s[j * HID + c0];
        p[j] = hv.x * wt.x + hv.y * wt.y + hv.z * wt.z + hv.w * wt.w;
    }
#pragma unroll
    for (int off = 32; off; off >>= 1)
#pragma unroll
        for (int j = 0; j < 8; j++) p[j] += __shfl_down(p[j], off);
    if (lane == 0) {
#pragma unroll
        for (int j = 0; j < 8; j++) a_att[n * 8 + j] = p[j];
    }
}

// ---------------------------------------------------------------- GAT edge-softmax + weighted aggregation
// T[n][hh*256+c] = sum_{j in N(n) ∪ {n}} alpha^hh_{nj} * h[j][c]
__global__ __launch_bounds__(256) void gat_agg_kernel(const float* __restrict__ h,
                                                      const float* __restrict__ a_att,
                                                      const int* __restrict__ row_start,
                                                      const int* __restrict__ col,
                                                      float* __restrict__ T) {
    int wave = threadIdx.x >> 6;
    int lane = threadIdx.x & 63;
    int n = blockIdx.x * 4 + wave;
    int start = row_start[n], end = row_start[n + 1];

    float adst[4], selfl[4], m[4];
#pragma unroll
    for (int hh = 0; hh < 4; hh++) {
        float as = a_att[n * 8 + hh];
        adst[hh] = a_att[n * 8 + 4 + hh];
        selfl[hh] = lrelu(as + adst[hh]);
        m[hh] = -INFINITY;
    }
    // pass 1: max over in-edges (lanes strided)
    for (int e = start + lane; e < end; e += 64) {
        int s = col[e];
#pragma unroll
        for (int hh = 0; hh < 4; hh++)
            m[hh] = fmaxf(m[hh], lrelu(a_att[s * 8 + hh] + adst[hh]));
    }
#pragma unroll
    for (int off = 32; off; off >>= 1)
#pragma unroll
        for (int hh = 0; hh < 4; hh++) m[hh] = fmaxf(m[hh], __shfl_down(m[hh], off));
#pragma unroll
    for (int hh = 0; hh < 4; hh++) {
        m[hh] = __shfl(m[hh], 0);
        m[hh] = fmaxf(m[hh], selfl[hh]);
    }
    // pass 2: denom
    float d[4] = {0.f, 0.f, 0.f, 0.f};
    for (int e = start + lane; e < end; e += 64) {
        int s = col[e];
#pragma unroll
        for (int hh = 0; hh < 4; hh++)
            d[hh] += __expf(lrelu(a_att[s * 8 + hh] + adst[hh]) - m[hh]);
    }
#pragma unroll
    for (int off = 32; off; off >>= 1)
#pragma unroll
        for (int hh = 0; hh < 4; hh++) d[hh] += __shfl_down(d[hh], off);
    float invd[4];
#pragma unroll
    for (int hh = 0; hh < 4; hh++) {
        d[hh] = __shfl(d[hh], 0) + __expf(selfl[hh] - m[hh]);
        invd[hh] = 1.f / d[hh];
    }
    // pass 3: weighted aggregation (all lanes per edge; lane covers cols lane*4..+3)
    int c0 = lane * 4;
    float4 hn = *(const float4*)(h + (size_t)n * HID + c0);
    float4 acc[4];
#pragma unroll
    for (int hh = 0; hh < 4; hh++) {
        float ws = __expf(selfl[hh] - m[hh]) * invd[hh];
        acc[hh] = make_float4(ws * hn.x, ws * hn.y, ws * hn.z, ws * hn.w);
    }
    for (int e = start; e < end; e++) {
        int s = col[e];
        float w[4];
#pragma unroll
        for (int hh = 0; hh < 4; hh++)
            w[hh] = __expf(lrelu(a_att[s * 8 + hh] + adst[hh]) - m[hh]) * invd[hh];
        float4 hv = *(const float4*)(h + (size_t)s * HID + c0);
#pragma unroll
        for (int hh = 0; hh < 4; hh++) {
            acc[hh].x = fmaf(w[hh], hv.x, acc[hh].x);
            acc[hh].y = fmaf(w[hh], hv.y, acc[hh].y);
            acc[hh].z = fmaf(w[hh], hv.z, acc[hh].z);
            acc[hh].w = fmaf(w[hh], hv.w, acc[hh].w);
        }
    }
#pragma unroll
    for (int hh = 0; hh < 4; hh++)
        *(float4*)(T + (size_t)n * (HEADS * HID) + hh * HID + c0) = acc[hh];
}

// ---------------------------------------------------------------- pool (mean per batch) + action head
__device__ __forceinline__ int lower_bound_i(const int* a, int n, int v) {
    int lo = 0, hi = n;
    while (lo < hi) {
        int mid = (lo + hi) >> 1;
        if (a[mid] < v) lo = mid + 1; else hi = mid;
    }
    return lo;
}

__global__ __launch_bounds__(256) void pool_head_kernel(const float* __restrict__ outn,
                                                        const int* __restrict__ batch,
                                                        const float* __restrict__ head_w,
                                                        const float* __restrict__ head_b,
                                                        float* __restrict__ out) {
    __shared__ float sm[HID];
    int b = blockIdx.x;
    int c = threadIdx.x;
    int lo = lower_bound_i(batch, N_NODES, b);
    int hi = lower_bound_i(batch, N_NODES, b + 1);
    int cnt = hi - lo;
    float s = 0.f;
    for (int n = lo; n < hi; n++) s += outn[(size_t)n * HID + c];
    sm[c] = s / (float)max(cnt, 1);
    __syncthreads();
    if (c < ACTIONS) {
        float acc = head_b[c];
        for (int k = 0; k < HID; k++) acc = fmaf(sm[k], head_w[k * ACTIONS + c], acc);
        out[b * ACTIONS + c] = acc;
    }
}

// ---------------------------------------------------------------- launcher
extern "C" void kernel_launch(void* const* d_in, const int* in_sizes, int n_in,
                              void* d_out, int out_size, void* d_ws, size_t ws_size,
                              hipStream_t stream) {
    const float* x        = (const float*)d_in[0];
    const int*   ei       = (const int*)d_in[1];
    const int*   batch    = (const int*)d_in[2];
    const float* sage_w_l = (const float*)d_in[3];
    const float* sage_b_l = (const float*)d_in[4];
    const float* sage_w_r = (const float*)d_in[5];
    const float* gat_w    = (const float*)d_in[6];
    const float* att_src  = (const float*)d_in[7];
    const float* att_dst  = (const float*)d_in[8];
    const float* gat_b    = (const float*)d_in[9];
    const float* head_w   = (const float*)d_in[10];
    const float* head_b   = (const float*)d_in[11];
    float* out = (float*)d_out;

    // workspace layout (all sizes multiple of 256 B)
    char* w = (char*)d_ws;
    float* xlr    = (float*)w; w += (size_t)N_NODES * IN_DIM * 4;          // 32 MB
    float* h      = (float*)w; w += (size_t)N_NODES * HID * 4;             // 16 MB
    float* T      = (float*)w; w += (size_t)N_NODES * HEADS * HID * 4;     // 64 MB
    float* outn   = (float*)w; w += (size_t)N_NODES * HID * 4;             // 16 MB
    float* a_att  = (float*)w; w += (size_t)N_NODES * 8 * 4;               // 512 KB
    float* wlr    = (float*)w; w += (size_t)IN_DIM * 2 * HID * 4;          // 1 MB
    float* wstack = (float*)w; w += (size_t)HEADS * HID * HID * 4;         // 1 MB
    float* watt   = (float*)w; w += (size_t)8 * HID * 4;                   // 8 KB
    int* deg      = (int*)w;   w += (size_t)N_NODES * 4;
    int* row_start= (int*)w;   w += (size_t)(N_NODES + 64) * 4;
    int* pos      = (int*)w;   w += (size_t)N_NODES * 4;
    int* col      = (int*)w;   w += (size_t)N_EDGES * 4;

    // --- weight packing (independent of graph) ---
    pack_wlr_kernel<<<(IN_DIM * 2 * HID) / 256, 256, 0, stream>>>(sage_w_l, sage_w_r, wlr);
    pack_wstack_kernel<<<(HEADS * HID * HID) / 256, 256, 0, stream>>>(gat_w, wstack);
    watt_kernel<<<8, 256, 0, stream>>>(gat_w, att_src, att_dst, watt);

    // --- CSR build (by dst) ---
    zero_int_kernel<<<(N_NODES + 255) / 256, 256, 0, stream>>>(deg, N_NODES);
    deg_kernel<<<N_EDGES / 256, 256, 0, stream>>>(ei, deg);
    scan_kernel<<<1, 256, 0, stream>>>(deg, row_start, pos);
    fill_kernel<<<N_EDGES / 256, 256, 0, stream>>>(ei, pos, col);

    // --- xlr = x @ [W_l | W_r] ---
    sgemm_kernel<<<dim3((2 * HID) / 128, N_NODES / 128), 256, 0, stream>>>(
        x, wlr, xlr, N_NODES, 2 * HID, IN_DIM, nullptr, 1.f, 0);

    // --- SAGE mean-agg + h = relu(...) + attention scalars ---
    sage_agg_kernel<<<N_NODES / 4, 256, 0, stream>>>(xlr, row_start, col, sage_b_l, watt, h, a_att);

    // --- GAT softmax + weighted aggregation of h ---
    gat_agg_kernel<<<N_NODES / 4, 256, 0, stream>>>(h, a_att, row_start, col, T);

    // --- out_nodes = relu(T @ Wstack * 0.25 + gat_b) ---
    sgemm_kernel<<<dim3(HID / 128, N_NODES / 128), 256, 0, stream>>>(
        T, wstack, outn, N_NODES, HID, HEADS * HID, gat_b, 0.25f, 1);

    // --- global mean pool + action head ---
    pool_head_kernel<<<NBATCH, 256, 0, stream>>>(outn, batch, head_w, head_b, out);
}

// Round 2
// 377.947 us; speedup vs baseline: 1.5327x; 1.5327x over previous
//
#include <hip/hip_runtime.h>
#include <math.h>

#define N_NODES 16384
#define N_EDGES 262144
#define IN_DIM  512
#define HID     256
#define HEADS   4
#define NBATCH  64
#define ACTIONS 32
#define NEG_SLOPE 0.2f

typedef __attribute__((ext_vector_type(8))) short short8;
typedef __attribute__((ext_vector_type(4))) float f32x4;

__device__ __forceinline__ float lrelu(float v) { return v > 0.f ? v : NEG_SLOPE * v; }

__device__ __forceinline__ unsigned short bf16_rne(float f) {
    union { float f; unsigned int u; } x; x.f = f;
    unsigned int u = x.u;
    unsigned int r = (u + 0x7FFFu + ((u >> 16) & 1u)) >> 16;
    return (unsigned short)r;
}

__device__ __forceinline__ void async_copy16(const unsigned short* g, unsigned short* l) {
    __builtin_amdgcn_global_load_lds(
        (const __attribute__((address_space(1))) unsigned int*)g,
        (__attribute__((address_space(3))) unsigned int*)l, 16, 0, 0);
}

// ---------------------------------------------------------------- utility
__global__ void zero_int_kernel(int* __restrict__ p, int n) {
    int i = blockIdx.x * 256 + threadIdx.x;
    if (i < n) p[i] = 0;
}

__global__ void f32_to_bf16_kernel(const float* __restrict__ in, unsigned short* __restrict__ out, int n) {
    int i = (blockIdx.x * 256 + threadIdx.x) * 4;
    if (i < n) {
        float4 v = *(const float4*)(in + i);
        ushort4 o;
        o.x = bf16_rne(v.x); o.y = bf16_rne(v.y); o.z = bf16_rne(v.z); o.w = bf16_rne(v.w);
        *(ushort4*)(out + i) = o;
    }
}

// Bt1[j][k] = wlr[k][j]: j<256 -> wl[k][j], else wr[k][j-256].  [512,512] bf16 row-major.
__global__ void pack_wlr_bt_kernel(const float* __restrict__ wl, const float* __restrict__ wr,
                                   unsigned short* __restrict__ bt) {
    int idx = blockIdx.x * 256 + threadIdx.x;   // 0 .. 512*512-1
    int j = idx >> 9;
    int k = idx & 511;
    float v = (j < HID) ? wl[k * HID + j] : wr[k * HID + (j - HID)];
    bt[idx] = bf16_rne(v);
}

// Bt2[c][h*256+k] = gat_w[k][h*256+c].  [256,1024] bf16 row-major.
__global__ void pack_wstack_bt_kernel(const float* __restrict__ gat_w, unsigned short* __restrict__ bt) {
    int idx = blockIdx.x * 256 + threadIdx.x;   // 0 .. 256*1024-1
    int c = idx >> 10;
    int r = idx & 1023;
    int h = r >> 8;
    int k = r & 255;
    bt[idx] = bf16_rne(gat_w[(size_t)k * (HEADS * HID) + h * HID + c]);
}

// watt[j][c]: j<4 -> W_h@att_src_h ; j>=4 -> W_h@att_dst_h  ([8][256] fp32)
__global__ void watt_kernel(const float* __restrict__ gat_w,
                            const float* __restrict__ att_src,
                            const float* __restrict__ att_dst,
                            float* __restrict__ watt) {
    int j = blockIdx.x;        // 0..7
    int c = threadIdx.x;       // 0..255
    int hh = j & 3;
    const float* att = (j < 4) ? (att_src + hh * HID) : (att_dst + hh * HID);
    float s = 0.f;
    for (int cc = 0; cc < HID; cc++)
        s += gat_w[(size_t)c * (HEADS * HID) + hh * HID + cc] * att[cc];
    watt[j * HID + c] = s;
}

// ---------------------------------------------------------------- CSR build
__global__ void deg_kernel(const int* __restrict__ ei, int* __restrict__ deg) {
    int e = blockIdx.x * 256 + threadIdx.x;
    if (e < N_EDGES) atomicAdd(&deg[ei[N_EDGES + e]], 1);
}

__global__ void scan_kernel(const int* __restrict__ deg, int* __restrict__ row_start,
                            int* __restrict__ pos) {
    __shared__ int part[256];
    int t = threadIdx.x;
    int base = t * 64;
    int s = 0;
    for (int i = 0; i < 64; i++) s += deg[base + i];
    part[t] = s;
    __syncthreads();
    if (t == 0) {
        int acc = 0;
        for (int i = 0; i < 256; i++) { int v = part[i]; part[i] = acc; acc += v; }
    }
    __syncthreads();
    int run = part[t];
    for (int i = 0; i < 64; i++) {
        row_start[base + i] = run;
        pos[base + i] = run;
        run += deg[base + i];
    }
    if (t == 255) row_start[N_NODES] = run;
}

__global__ void fill_kernel(const int* __restrict__ ei, int* __restrict__ pos,
                            int* __restrict__ col) {
    int e = blockIdx.x * 256 + threadIdx.x;
    if (e < N_EDGES) {
        int s = ei[e];
        int d = ei[N_EDGES + e];
        int p = atomicAdd(&pos[d], 1);
        col[p] = s;
    }
}

// ---------------------------------------------------------------- bf16 MFMA GEMM (m97 structure)
// A: [M,K] bf16 row-major.  Bt: [N,K] bf16 row-major (i.e. B transposed).
// C[m][n] = sum_k A[m][k]*Bt[n][k].  mode 0: C raw fp32.  mode 1: relu(C*scale + bias[n]).
// 128x128 tile, BK=32, 4 waves in 2x2, each wave 64x64 via 4x4 mfma_f32_16x16x32_bf16.
#define BM 128
#define BN 128
#define BK 32

__global__ __launch_bounds__(256) void gemm_bt_kernel(const unsigned short* __restrict__ A,
                                                      const unsigned short* __restrict__ Bt,
                                                      float* __restrict__ C,
                                                      int M, int Nn, int K,
                                                      const float* __restrict__ bias,
                                                      float scale, int mode) {
    __shared__ __align__(16) unsigned short As[BM * BK];  // row stride BK elems (64 B)
    __shared__ __align__(16) unsigned short Bs[BN * BK];

    int tid  = threadIdx.x;
    int wv   = tid >> 6;
    int lane = tid & 63;
    int m0 = blockIdx.y * BM;
    int n0 = blockIdx.x * BN;
    int wm = (wv & 1) * 64;
    int wn = (wv >> 1) * 64;

    // staging: thread t covers LDS elems [j*2048 + t*8, +8) for issue j in {0,1}
    int srow = tid >> 2;            // 0..63
    int scol = (tid & 3) * 8;       // k-elem offset (16 B granule)
    const unsigned short* Ag0 = A  + (size_t)(m0 + srow) * K + scol;
    const unsigned short* Ag1 = A  + (size_t)(m0 + 64 + srow) * K + scol;
    const unsigned short* Bg0 = Bt + (size_t)(n0 + srow) * K + scol;
    const unsigned short* Bg1 = Bt + (size_t)(n0 + 64 + srow) * K + scol;
    unsigned short* Al0 = As + wv * 512;          // wave-uniform LDS bases
    unsigned short* Al1 = As + 2048 + wv * 512;
    unsigned short* Bl0 = Bs + wv * 512;
    unsigned short* Bl1 = Bs + 2048 + wv * 512;

    // fragment read addresses
    int fr   = lane & 15;           // row within 16-tile
    int fk   = (lane >> 4) * 8;     // k-elem offset
    f32x4 acc[4][4] = {};

    for (int kt = 0; kt < K; kt += BK) {
        async_copy16(Ag0 + kt, Al0);
        async_copy16(Ag1 + kt, Al1);
        async_copy16(Bg0 + kt, Bl0);
        async_copy16(Bg1 + kt, Bl1);
        __syncthreads();

        short8 af[4], bf[4];
#pragma unroll
        for (int mi = 0; mi < 4; mi++)
            af[mi] = *(const short8*)&As[(wm + mi * 16 + fr) * BK + fk];
#pragma unroll
        for (int ni = 0; ni < 4; ni++)
            bf[ni] = *(const short8*)&Bs[(wn + ni * 16 + fr) * BK + fk];
#pragma unroll
        for (int mi = 0; mi < 4; mi++)
#pragma unroll
            for (int ni = 0; ni < 4; ni++)
                acc[mi][ni] = __builtin_amdgcn_mfma_f32_16x16x32_bf16(af[mi], bf[ni], acc[mi][ni], 0, 0, 0);
        __syncthreads();
    }

    // epilogue: C/D layout col=lane&15, row=(lane>>4)*4+reg
    int cr = (lane >> 4) * 4;
    int cc = lane & 15;
#pragma unroll
    for (int mi = 0; mi < 4; mi++) {
#pragma unroll
        for (int ni = 0; ni < 4; ni++) {
            int gc = n0 + wn + ni * 16 + cc;
            float b = (mode == 1) ? bias[gc] : 0.f;
#pragma unroll
            for (int r = 0; r < 4; r++) {
                int gr = m0 + wm + mi * 16 + cr + r;
                float v = acc[mi][ni][r];
                if (mode == 1) v = fmaxf(fmaf(v, scale, b), 0.f);
                C[(size_t)gr * Nn + gc] = v;
            }
        }
    }
}

// ---------------------------------------------------------------- SAGE aggregation + h + attention scalars
__global__ __launch_bounds__(256) void sage_agg_kernel(const float* __restrict__ xlr,
                                                       const int* __restrict__ row_start,
                                                       const int* __restrict__ col,
                                                       const float* __restrict__ b_l,
                                                       const float* __restrict__ watt,
                                                       float* __restrict__ h,
                                                       float* __restrict__ a_att) {
    __shared__ float watt_s[8 * HID];
    for (int i = threadIdx.x; i < 8 * HID; i += 256) watt_s[i] = watt[i];
    __syncthreads();

    int wave = threadIdx.x >> 6;
    int lane = threadIdx.x & 63;
    int n = blockIdx.x * 4 + wave;
    int start = row_start[n], end = row_start[n + 1];
    int c0 = lane * 4;

    float4 acc = make_float4(0.f, 0.f, 0.f, 0.f);
    for (int e = start; e < end; e++) {
        int s = col[e];
        float4 v = *(const float4*)(xlr + (size_t)s * IN_DIM + c0);
        acc.x += v.x; acc.y += v.y; acc.z += v.z; acc.w += v.w;
    }
    float inv = 1.f / (float)max(end - start, 1);
    float4 xr = *(const float4*)(xlr + (size_t)n * IN_DIM + HID + c0);
    float4 bl = *(const float4*)(b_l + c0);
    float4 hv;
    hv.x = fmaxf(fmaf(acc.x, inv, bl.x + xr.x), 0.f);
    hv.y = fmaxf(fmaf(acc.y, inv, bl.y + xr.y), 0.f);
    hv.z = fmaxf(fmaf(acc.z, inv, bl.z + xr.z), 0.f);
    hv.w = fmaxf(fmaf(acc.w, inv, bl.w + xr.w), 0.f);
    *(float4*)(h + (size_t)n * HID + c0) = hv;

    float p[8];
#pragma unroll
    for (int j = 0; j < 8; j++) {
        float4 wt = *(const float4*)&watt_s[j * HID + c0];
        p[j] = hv.x * wt.x + hv.y * wt.y + hv.z * wt.z + hv.w * wt.w;
    }
#pragma unroll
    for (int off = 32; off; off >>= 1)
#pragma unroll
        for (int j = 0; j < 8; j++) p[j] += __shfl_down(p[j], off);
    if (lane == 0) {
#pragma unroll
        for (int j = 0; j < 8; j++) a_att[n * 8 + j] = p[j];
    }
}

// ---------------------------------------------------------------- GAT edge-softmax + weighted aggregation
// T[n][hh*256+c] (bf16) = sum_{j in N(n) ∪ {n}} alpha^hh_{nj} * h[j][c]
__global__ __launch_bounds__(256) void gat_agg_kernel(const float* __restrict__ h,
                                                      const float* __restrict__ a_att,
                                                      const int* __restrict__ row_start,
                                                      const int* __restrict__ col,
                                                      unsigned short* __restrict__ T) {
    int wave = threadIdx.x >> 6;
    int lane = threadIdx.x & 63;
    int n = blockIdx.x * 4 + wave;
    int start = row_start[n], end = row_start[n + 1];

    float adst[4], selfl[4], m[4];
#pragma unroll
    for (int hh = 0; hh < 4; hh++) {
        float as = a_att[n * 8 + hh];
        adst[hh] = a_att[n * 8 + 4 + hh];
        selfl[hh] = lrelu(as + adst[hh]);
        m[hh] = -INFINITY;
    }
    for (int e = start + lane; e < end; e += 64) {
        int s = col[e];
#pragma unroll
        for (int hh = 0; hh < 4; hh++)
            m[hh] = fmaxf(m[hh], lrelu(a_att[s * 8 + hh] + adst[hh]));
    }
#pragma unroll
    for (int off = 32; off; off >>= 1)
#pragma unroll
        for (int hh = 0; hh < 4; hh++) m[hh] = fmaxf(m[hh], __shfl_down(m[hh], off));
#pragma unroll
    for (int hh = 0; hh < 4; hh++) {
        m[hh] = __shfl(m[hh], 0);
        m[hh] = fmaxf(m[hh], selfl[hh]);
    }
    float d[4] = {0.f, 0.f, 0.f, 0.f};
    for (int e = start + lane; e < end; e += 64) {
        int s = col[e];
#pragma unroll
        for (int hh = 0; hh < 4; hh++)
            d[hh] += __expf(lrelu(a_att[s * 8 + hh] + adst[hh]) - m[hh]);
    }
#pragma unroll
    for (int off = 32; off; off >>= 1)
#pragma unroll
        for (int hh = 0; hh < 4; hh++) d[hh] += __shfl_down(d[hh], off);
    float invd[4];
#pragma unroll
    for (int hh = 0; hh < 4; hh++) {
        d[hh] = __shfl(d[hh], 0) + __expf(selfl[hh] - m[hh]);
        invd[hh] = 1.f / d[hh];
    }
    int c0 = lane * 4;
    float4 hn = *(const float4*)(h + (size_t)n * HID + c0);
    float4 acc[4];
#pragma unroll
    for (int hh = 0; hh < 4; hh++) {
        float ws = __expf(selfl[hh] - m[hh]) * invd[hh];
        acc[hh] = make_float4(ws * hn.x, ws * hn.y, ws * hn.z, ws * hn.w);
    }
    for (int e = start; e < end; e++) {
        int s = col[e];
        float w[4];
#pragma unroll
        for (int hh = 0; hh < 4; hh++)
            w[hh] = __expf(lrelu(a_att[s * 8 + hh] + adst[hh]) - m[hh]) * invd[hh];
        float4 hv = *(const float4*)(h + (size_t)s * HID + c0);
#pragma unroll
        for (int hh = 0; hh < 4; hh++) {
            acc[hh].x = fmaf(w[hh], hv.x, acc[hh].x);
            acc[hh].y = fmaf(w[hh], hv.y, acc[hh].y);
            acc[hh].z = fmaf(w[hh], hv.z, acc[hh].z);
            acc[hh].w = fmaf(w[hh], hv.w, acc[hh].w);
        }
    }
#pragma unroll
    for (int hh = 0; hh < 4; hh++) {
        ushort4 o;
        o.x = bf16_rne(acc[hh].x); o.y = bf16_rne(acc[hh].y);
        o.z = bf16_rne(acc[hh].z); o.w = bf16_rne(acc[hh].w);
        *(ushort4*)(T + (size_t)n * (HEADS * HID) + hh * HID + c0) = o;
    }
}

// ---------------------------------------------------------------- pool (mean per batch) + action head
__device__ __forceinline__ int lower_bound_i(const int* a, int n, int v) {
    int lo = 0, hi = n;
    while (lo < hi) {
        int mid = (lo + hi) >> 1;
        if (a[mid] < v) lo = mid + 1; else hi = mid;
    }
    return lo;
}

__global__ __launch_bounds__(256) void pool_head_kernel(const float* __restrict__ outn,
                                                        const int* __restrict__ batch,
                                                        const float* __restrict__ head_w,
                                                        const float* __restrict__ head_b,
                                                        float* __restrict__ out) {
    __shared__ float sm[HID];
    int b = blockIdx.x;
    int c = threadIdx.x;
    int lo = lower_bound_i(batch, N_NODES, b);
    int hi = lower_bound_i(batch, N_NODES, b + 1);
    int cnt = hi - lo;
    float s = 0.f;
    for (int n = lo; n < hi; n++) s += outn[(size_t)n * HID + c];
    sm[c] = s / (float)max(cnt, 1);
    __syncthreads();
    if (c < ACTIONS) {
        float acc = head_b[c];
        for (int k = 0; k < HID; k++) acc = fmaf(sm[k], head_w[k * ACTIONS + c], acc);
        out[b * ACTIONS + c] = acc;
    }
}

// ---------------------------------------------------------------- launcher
extern "C" void kernel_launch(void* const* d_in, const int* in_sizes, int n_in,
                              void* d_out, int out_size, void* d_ws, size_t ws_size,
                              hipStream_t stream) {
    const float* x        = (const float*)d_in[0];
    const int*   ei       = (const int*)d_in[1];
    const int*   batch    = (const int*)d_in[2];
    const float* sage_w_l = (const float*)d_in[3];
    const float* sage_b_l = (const float*)d_in[4];
    const float* sage_w_r = (const float*)d_in[5];
    const float* gat_w    = (const float*)d_in[6];
    const float* att_src  = (const float*)d_in[7];
    const float* att_dst  = (const float*)d_in[8];
    const float* gat_b    = (const float*)d_in[9];
    const float* head_w   = (const float*)d_in[10];
    const float* head_b   = (const float*)d_in[11];
    float* out = (float*)d_out;

    // workspace layout
    char* w = (char*)d_ws;
    float* xlr    = (float*)w; w += (size_t)N_NODES * IN_DIM * 4;            // 32 MB fp32
    float* h      = (float*)w; w += (size_t)N_NODES * HID * 4;               // 16 MB
    float* outn   = (float*)w; w += (size_t)N_NODES * HID * 4;               // 16 MB
    float* a_att  = (float*)w; w += (size_t)N_NODES * 8 * 4;                 // 512 KB
    float* watt   = (float*)w; w += (size_t)8 * HID * 4;                     // 8 KB
    unsigned short* xb  = (unsigned short*)w; w += (size_t)N_NODES * IN_DIM * 2;          // 16 MB bf16
    unsigned short* T   = (unsigned short*)w; w += (size_t)N_NODES * HEADS * HID * 2;     // 32 MB bf16
    unsigned short* bt1 = (unsigned short*)w; w += (size_t)(2 * HID) * IN_DIM * 2;        // 512 KB
    unsigned short* bt2 = (unsigned short*)w; w += (size_t)HID * (HEADS * HID) * 2;       // 512 KB
    int* deg      = (int*)w;   w += (size_t)N_NODES * 4;
    int* row_start= (int*)w;   w += (size_t)(N_NODES + 64) * 4;
    int* pos      = (int*)w;   w += (size_t)N_NODES * 4;
    int* col      = (int*)w;   w += (size_t)N_EDGES * 4;

    // --- weight packing / input conversion ---
    f32_to_bf16_kernel<<<(N_NODES * IN_DIM / 4) / 256, 256, 0, stream>>>(x, xb, N_NODES * IN_DIM);
    pack_wlr_bt_kernel<<<(2 * HID * IN_DIM) / 256, 256, 0, stream>>>(sage_w_l, sage_w_r, bt1);
    pack_wstack_bt_kernel<<<(HID * HEADS * HID) / 256, 256, 0, stream>>>(gat_w, bt2);
    watt_kernel<<<8, 256, 0, stream>>>(gat_w, att_src, att_dst, watt);

    // --- CSR build (by dst) ---
    zero_int_kernel<<<(N_NODES + 255) / 256, 256, 0, stream>>>(deg, N_NODES);
    deg_kernel<<<N_EDGES / 256, 256, 0, stream>>>(ei, deg);
    scan_kernel<<<1, 256, 0, stream>>>(deg, row_start, pos);
    fill_kernel<<<N_EDGES / 256, 256, 0, stream>>>(ei, pos, col);

    // --- xlr = x @ [W_l | W_r]  (bf16 MFMA) ---
    gemm_bt_kernel<<<dim3((2 * HID) / BN, N_NODES / BM), 256, 0, stream>>>(
        xb, bt1, xlr, N_NODES, 2 * HID, IN_DIM, nullptr, 1.f, 0);

    // --- SAGE mean-agg + h = relu(...) + attention scalars ---
    sage_agg_kernel<<<N_NODES / 4, 256, 0, stream>>>(xlr, row_start, col, sage_b_l, watt, h, a_att);

    // --- GAT softmax + weighted aggregation of h (writes bf16 T) ---
    gat_agg_kernel<<<N_NODES / 4, 256, 0, stream>>>(h, a_att, row_start, col, T);

    // --- out_nodes = relu(T @ Wstack * 0.25 + gat_b)  (bf16 MFMA) ---
    gemm_bt_kernel<<<dim3(HID / BN, N_NODES / BM), 256, 0, stream>>>(
        T, bt2, outn, N_NODES, HID, HEADS * HID, gat_b, 0.25f, 1);

    // --- global mean pool + action head ---
    pool_head_kernel<<<NBATCH, 256, 0, stream>>>(outn, batch, head_w, head_b, out);
}

// Round 3
// 327.276 us; speedup vs baseline: 1.7700x; 1.1548x over previous
//
#include <hip/hip_runtime.h>
#include <math.h>

#define N_NODES 16384
#define N_EDGES 262144
#define IN_DIM  512
#define HID     256
#define HEADS   4
#define NBATCH  64
#define ACTIONS 32
#define NEG_SLOPE 0.2f

typedef __attribute__((ext_vector_type(8))) short short8;
typedef __attribute__((ext_vector_type(4))) float f32x4;

__device__ __forceinline__ float lrelu(float v) { return v > 0.f ? v : NEG_SLOPE * v; }

__device__ __forceinline__ unsigned short bf16_rne(float f) {
    union { float f; unsigned int u; } x; x.f = f;
    unsigned int u = x.u;
    unsigned int r = (u + 0x7FFFu + ((u >> 16) & 1u)) >> 16;
    return (unsigned short)r;
}

__device__ __forceinline__ float bf16_to_f32(unsigned short s) {
    union { unsigned int u; float f; } x; x.u = (unsigned int)s << 16;
    return x.f;
}

__device__ __forceinline__ float4 bf4_to_f4(ushort4 u) {
    return make_float4(bf16_to_f32(u.x), bf16_to_f32(u.y), bf16_to_f32(u.z), bf16_to_f32(u.w));
}

__device__ __forceinline__ void async_copy16(const unsigned short* g, unsigned short* l) {
    __builtin_amdgcn_global_load_lds(
        (const __attribute__((address_space(1))) unsigned int*)g,
        (__attribute__((address_space(3))) unsigned int*)l, 16, 0, 0);
}

// ---------------------------------------------------------------- utility
__global__ void zero_int_kernel(int* __restrict__ p, int n) {
    int i = blockIdx.x * 256 + threadIdx.x;
    if (i < n) p[i] = 0;
}

__global__ void zero_f32_kernel(float* __restrict__ p, int n) {
    int i = blockIdx.x * 256 + threadIdx.x;
    if (i < n) p[i] = 0.f;
}

__global__ void f32_to_bf16_kernel(const float* __restrict__ in, unsigned short* __restrict__ out, int n) {
    int i = (blockIdx.x * 256 + threadIdx.x) * 4;
    if (i < n) {
        float4 v = *(const float4*)(in + i);
        ushort4 o;
        o.x = bf16_rne(v.x); o.y = bf16_rne(v.y); o.z = bf16_rne(v.z); o.w = bf16_rne(v.w);
        *(ushort4*)(out + i) = o;
    }
}

// Bt1[j][k] = wlr[k][j]: j<256 -> wl[k][j], else wr[k][j-256].  [512,512] bf16 row-major.
__global__ void pack_wlr_bt_kernel(const float* __restrict__ wl, const float* __restrict__ wr,
                                   unsigned short* __restrict__ bt) {
    int idx = blockIdx.x * 256 + threadIdx.x;
    int j = idx >> 9;
    int k = idx & 511;
    float v = (j < HID) ? wl[k * HID + j] : wr[k * HID + (j - HID)];
    bt[idx] = bf16_rne(v);
}

// Bt2[c][h*256+k] = gat_w[k][h*256+c].  [256,1024] bf16 row-major.
__global__ void pack_wstack_bt_kernel(const float* __restrict__ gat_w, unsigned short* __restrict__ bt) {
    int idx = blockIdx.x * 256 + threadIdx.x;
    int c = idx >> 10;
    int r = idx & 1023;
    int h = r >> 8;
    int k = r & 255;
    bt[idx] = bf16_rne(gat_w[(size_t)k * (HEADS * HID) + h * HID + c]);
}

// watt[j][c]: j<4 -> W_h@att_src_h ; j>=4 -> W_h@att_dst_h  ([8][256] fp32)
__global__ void watt_kernel(const float* __restrict__ gat_w,
                            const float* __restrict__ att_src,
                            const float* __restrict__ att_dst,
                            float* __restrict__ watt) {
    int j = blockIdx.x;
    int c = threadIdx.x;
    int hh = j & 3;
    const float* att = (j < 4) ? (att_src + hh * HID) : (att_dst + hh * HID);
    float s = 0.f;
    for (int cc = 0; cc < HID; cc++)
        s += gat_w[(size_t)c * (HEADS * HID) + hh * HID + cc] * att[cc];
    watt[j * HID + c] = s;
}

// ---------------------------------------------------------------- CSR build
__global__ void deg_kernel(const int* __restrict__ ei, int* __restrict__ deg) {
    int e = blockIdx.x * 256 + threadIdx.x;
    if (e < N_EDGES) atomicAdd(&deg[ei[N_EDGES + e]], 1);
}

__global__ void scan_kernel(const int* __restrict__ deg, int* __restrict__ row_start,
                            int* __restrict__ pos) {
    __shared__ int part[256];
    int t = threadIdx.x;
    int base = t * 64;
    int s = 0;
    for (int i = 0; i < 64; i++) s += deg[base + i];
    part[t] = s;
    __syncthreads();
    if (t == 0) {
        int acc = 0;
        for (int i = 0; i < 256; i++) { int v = part[i]; part[i] = acc; acc += v; }
    }
    __syncthreads();
    int run = part[t];
    for (int i = 0; i < 64; i++) {
        row_start[base + i] = run;
        pos[base + i] = run;
        run += deg[base + i];
    }
    if (t == 255) row_start[N_NODES] = run;
}

__global__ void fill_kernel(const int* __restrict__ ei, int* __restrict__ pos,
                            int* __restrict__ col) {
    int e = blockIdx.x * 256 + threadIdx.x;
    if (e < N_EDGES) {
        int s = ei[e];
        int d = ei[N_EDGES + e];
        int p = atomicAdd(&pos[d], 1);
        col[p] = s;
    }
}

// ---------------------------------------------------------------- bf16 MFMA GEMM (m97 structure)
// A: [M,K] bf16 row-major.  Bt: [N,K] bf16 row-major.
// mode 0: write bf16 to Cb.  mode 1: write relu(C*scale + bias[n]) fp32 to Cf.
#define BM 128
#define BN 128
#define BK 32

__global__ __launch_bounds__(256) void gemm_bt_kernel(const unsigned short* __restrict__ A,
                                                      const unsigned short* __restrict__ Bt,
                                                      float* __restrict__ Cf,
                                                      unsigned short* __restrict__ Cb,
                                                      int M, int Nn, int K,
                                                      const float* __restrict__ bias,
                                                      float scale, int mode) {
    __shared__ __align__(16) unsigned short As[BM * BK];
    __shared__ __align__(16) unsigned short Bs[BN * BK];

    int tid  = threadIdx.x;
    int wv   = tid >> 6;
    int lane = tid & 63;
    int m0 = blockIdx.y * BM;
    int n0 = blockIdx.x * BN;
    int wm = (wv & 1) * 64;
    int wn = (wv >> 1) * 64;

    int srow = tid >> 2;
    int scol = (tid & 3) * 8;
    const unsigned short* Ag0 = A  + (size_t)(m0 + srow) * K + scol;
    const unsigned short* Ag1 = A  + (size_t)(m0 + 64 + srow) * K + scol;
    const unsigned short* Bg0 = Bt + (size_t)(n0 + srow) * K + scol;
    const unsigned short* Bg1 = Bt + (size_t)(n0 + 64 + srow) * K + scol;
    unsigned short* Al0 = As + wv * 512;
    unsigned short* Al1 = As + 2048 + wv * 512;
    unsigned short* Bl0 = Bs + wv * 512;
    unsigned short* Bl1 = Bs + 2048 + wv * 512;

    int fr   = lane & 15;
    int fk   = (lane >> 4) * 8;
    f32x4 acc[4][4] = {};

    for (int kt = 0; kt < K; kt += BK) {
        async_copy16(Ag0 + kt, Al0);
        async_copy16(Ag1 + kt, Al1);
        async_copy16(Bg0 + kt, Bl0);
        async_copy16(Bg1 + kt, Bl1);
        __syncthreads();

        short8 af[4], bf[4];
#pragma unroll
        for (int mi = 0; mi < 4; mi++)
            af[mi] = *(const short8*)&As[(wm + mi * 16 + fr) * BK + fk];
#pragma unroll
        for (int ni = 0; ni < 4; ni++)
            bf[ni] = *(const short8*)&Bs[(wn + ni * 16 + fr) * BK + fk];
#pragma unroll
        for (int mi = 0; mi < 4; mi++)
#pragma unroll
            for (int ni = 0; ni < 4; ni++)
                acc[mi][ni] = __builtin_amdgcn_mfma_f32_16x16x32_bf16(af[mi], bf[ni], acc[mi][ni], 0, 0, 0);
        __syncthreads();
    }

    // epilogue: C/D layout col=lane&15, row=(lane>>4)*4+reg
    int cr = (lane >> 4) * 4;
    int cc = lane & 15;
#pragma unroll
    for (int mi = 0; mi < 4; mi++) {
#pragma unroll
        for (int ni = 0; ni < 4; ni++) {
            int gc = n0 + wn + ni * 16 + cc;
            float b = (mode == 1) ? bias[gc] : 0.f;
#pragma unroll
            for (int r = 0; r < 4; r++) {
                int gr = m0 + wm + mi * 16 + cr + r;
                float v = acc[mi][ni][r];
                if (mode == 1) {
                    Cf[(size_t)gr * Nn + gc] = fmaxf(fmaf(v, scale, b), 0.f);
                } else {
                    Cb[(size_t)gr * Nn + gc] = bf16_rne(v);
                }
            }
        }
    }
}

// ---------------------------------------------------------------- SAGE aggregation + h + attention scalars
// xlr bf16 [N,512]; h_out bf16 [N,256]; a_att fp32 [N,8]
__global__ __launch_bounds__(256) void sage_agg_kernel(const unsigned short* __restrict__ xlr,
                                                       const int* __restrict__ row_start,
                                                       const int* __restrict__ col,
                                                       const float* __restrict__ b_l,
                                                       const float* __restrict__ watt,
                                                       unsigned short* __restrict__ hb,
                                                       float* __restrict__ a_att) {
    __shared__ float watt_s[8 * HID];
    for (int i = threadIdx.x; i < 8 * HID; i += 256) watt_s[i] = watt[i];
    __syncthreads();

    int wave = threadIdx.x >> 6;
    int lane = threadIdx.x & 63;
    int n = blockIdx.x * 4 + wave;
    int start = row_start[n], end = row_start[n + 1];
    int c0 = lane * 4;

    float4 acc = make_float4(0.f, 0.f, 0.f, 0.f);
    for (int e = start; e < end; e++) {
        int s = col[e];
        float4 v = bf4_to_f4(*(const ushort4*)(xlr + (size_t)s * IN_DIM + c0));
        acc.x += v.x; acc.y += v.y; acc.z += v.z; acc.w += v.w;
    }
    float inv = 1.f / (float)max(end - start, 1);
    float4 xr = bf4_to_f4(*(const ushort4*)(xlr + (size_t)n * IN_DIM + HID + c0));
    float4 bl = *(const float4*)(b_l + c0);
    float4 hv;
    hv.x = fmaxf(fmaf(acc.x, inv, bl.x + xr.x), 0.f);
    hv.y = fmaxf(fmaf(acc.y, inv, bl.y + xr.y), 0.f);
    hv.z = fmaxf(fmaf(acc.z, inv, bl.z + xr.z), 0.f);
    hv.w = fmaxf(fmaf(acc.w, inv, bl.w + xr.w), 0.f);
    ushort4 ho;
    ho.x = bf16_rne(hv.x); ho.y = bf16_rne(hv.y); ho.z = bf16_rne(hv.z); ho.w = bf16_rne(hv.w);
    *(ushort4*)(hb + (size_t)n * HID + c0) = ho;

    float p[8];
#pragma unroll
    for (int j = 0; j < 8; j++) {
        float4 wt = *(const float4*)&watt_s[j * HID + c0];
        p[j] = hv.x * wt.x + hv.y * wt.y + hv.z * wt.z + hv.w * wt.w;
    }
#pragma unroll
    for (int off = 32; off; off >>= 1)
#pragma unroll
        for (int j = 0; j < 8; j++) p[j] += __shfl_down(p[j], off);
    if (lane == 0) {
#pragma unroll
        for (int j = 0; j < 8; j++) a_att[n * 8 + j] = p[j];
    }
}

// ---------------------------------------------------------------- GAT edge-softmax + weighted aggregation
// T[n][hh*256+c] (bf16) = sum_{j in N(n) ∪ {n}} alpha^hh_{nj} * h[j][c]
__global__ __launch_bounds__(256) void gat_agg_kernel(const unsigned short* __restrict__ hb,
                                                      const float* __restrict__ a_att,
                                                      const int* __restrict__ row_start,
                                                      const int* __restrict__ col,
                                                      unsigned short* __restrict__ T) {
    int wave = threadIdx.x >> 6;
    int lane = threadIdx.x & 63;
    int n = blockIdx.x * 4 + wave;
    int start = row_start[n], end = row_start[n + 1];

    float adst[4], selfl[4], m[4];
#pragma unroll
    for (int hh = 0; hh < 4; hh++) {
        float as = a_att[n * 8 + hh];
        adst[hh] = a_att[n * 8 + 4 + hh];
        selfl[hh] = lrelu(as + adst[hh]);
        m[hh] = -INFINITY;
    }
    for (int e = start + lane; e < end; e += 64) {
        int s = col[e];
#pragma unroll
        for (int hh = 0; hh < 4; hh++)
            m[hh] = fmaxf(m[hh], lrelu(a_att[s * 8 + hh] + adst[hh]));
    }
#pragma unroll
    for (int off = 32; off; off >>= 1)
#pragma unroll
        for (int hh = 0; hh < 4; hh++) m[hh] = fmaxf(m[hh], __shfl_down(m[hh], off));
#pragma unroll
    for (int hh = 0; hh < 4; hh++) {
        m[hh] = __shfl(m[hh], 0);
        m[hh] = fmaxf(m[hh], selfl[hh]);
    }
    float d[4] = {0.f, 0.f, 0.f, 0.f};
    for (int e = start + lane; e < end; e += 64) {
        int s = col[e];
#pragma unroll
        for (int hh = 0; hh < 4; hh++)
            d[hh] += __expf(lrelu(a_att[s * 8 + hh] + adst[hh]) - m[hh]);
    }
#pragma unroll
    for (int off = 32; off; off >>= 1)
#pragma unroll
        for (int hh = 0; hh < 4; hh++) d[hh] += __shfl_down(d[hh], off);
    float invd[4];
#pragma unroll
    for (int hh = 0; hh < 4; hh++) {
        d[hh] = __shfl(d[hh], 0) + __expf(selfl[hh] - m[hh]);
        invd[hh] = 1.f / d[hh];
    }
    int c0 = lane * 4;
    float4 hn = bf4_to_f4(*(const ushort4*)(hb + (size_t)n * HID + c0));
    float4 acc[4];
#pragma unroll
    for (int hh = 0; hh < 4; hh++) {
        float ws = __expf(selfl[hh] - m[hh]) * invd[hh];
        acc[hh] = make_float4(ws * hn.x, ws * hn.y, ws * hn.z, ws * hn.w);
    }
    for (int e = start; e < end; e++) {
        int s = col[e];
        float w[4];
#pragma unroll
        for (int hh = 0; hh < 4; hh++)
            w[hh] = __expf(lrelu(a_att[s * 8 + hh] + adst[hh]) - m[hh]) * invd[hh];
        float4 hv = bf4_to_f4(*(const ushort4*)(hb + (size_t)s * HID + c0));
#pragma unroll
        for (int hh = 0; hh < 4; hh++) {
            acc[hh].x = fmaf(w[hh], hv.x, acc[hh].x);
            acc[hh].y = fmaf(w[hh], hv.y, acc[hh].y);
            acc[hh].z = fmaf(w[hh], hv.z, acc[hh].z);
            acc[hh].w = fmaf(w[hh], hv.w, acc[hh].w);
        }
    }
#pragma unroll
    for (int hh = 0; hh < 4; hh++) {
        ushort4 o;
        o.x = bf16_rne(acc[hh].x); o.y = bf16_rne(acc[hh].y);
        o.z = bf16_rne(acc[hh].z); o.w = bf16_rne(acc[hh].w);
        *(ushort4*)(T + (size_t)n * (HEADS * HID) + hh * HID + c0) = o;
    }
}

// ---------------------------------------------------------------- pool: partial sums (256 blocks) + head
__global__ __launch_bounds__(256) void pool_partial_kernel(const float* __restrict__ outn,
                                                           const int* __restrict__ batch,
                                                           float* __restrict__ pooled) {
    int c = threadIdx.x;
    int n0 = blockIdx.x * 64;
    int cur = batch[n0];
    float acc = 0.f;
    for (int i = 0; i < 64; i++) {
        int n = n0 + i;
        int b = batch[n];
        if (b != cur) {
            atomicAdd(&pooled[cur * HID + c], acc);
            acc = 0.f;
            cur = b;
        }
        acc += outn[(size_t)n * HID + c];
    }
    atomicAdd(&pooled[cur * HID + c], acc);
}

__device__ __forceinline__ int lower_bound_i(const int* a, int n, int v) {
    int lo = 0, hi = n;
    while (lo < hi) {
        int mid = (lo + hi) >> 1;
        if (a[mid] < v) lo = mid + 1; else hi = mid;
    }
    return lo;
}

__global__ __launch_bounds__(256) void head_kernel(const float* __restrict__ pooled,
                                                   const int* __restrict__ batch,
                                                   const float* __restrict__ head_w,
                                                   const float* __restrict__ head_b,
                                                   float* __restrict__ out) {
    __shared__ float sm[HID];
    int b = blockIdx.x;
    int c = threadIdx.x;
    int lo = lower_bound_i(batch, N_NODES, b);
    int hi = lower_bound_i(batch, N_NODES, b + 1);
    int cnt = hi - lo;
    sm[c] = pooled[b * HID + c] / (float)max(cnt, 1);
    __syncthreads();
    if (c < ACTIONS) {
        float acc = head_b[c];
        for (int k = 0; k < HID; k++) acc = fmaf(sm[k], head_w[k * ACTIONS + c], acc);
        out[b * ACTIONS + c] = acc;
    }
}

// ---------------------------------------------------------------- launcher
extern "C" void kernel_launch(void* const* d_in, const int* in_sizes, int n_in,
                              void* d_out, int out_size, void* d_ws, size_t ws_size,
                              hipStream_t stream) {
    const float* x        = (const float*)d_in[0];
    const int*   ei       = (const int*)d_in[1];
    const int*   batch    = (const int*)d_in[2];
    const float* sage_w_l = (const float*)d_in[3];
    const float* sage_b_l = (const float*)d_in[4];
    const float* sage_w_r = (const float*)d_in[5];
    const float* gat_w    = (const float*)d_in[6];
    const float* att_src  = (const float*)d_in[7];
    const float* att_dst  = (const float*)d_in[8];
    const float* gat_b    = (const float*)d_in[9];
    const float* head_w   = (const float*)d_in[10];
    const float* head_b   = (const float*)d_in[11];
    float* out = (float*)d_out;

    // workspace layout
    char* w = (char*)d_ws;
    float* outn   = (float*)w; w += (size_t)N_NODES * HID * 4;               // 16 MB
    float* a_att  = (float*)w; w += (size_t)N_NODES * 8 * 4;                 // 512 KB
    float* watt   = (float*)w; w += (size_t)8 * HID * 4;                     // 8 KB
    float* pooled = (float*)w; w += (size_t)NBATCH * HID * 4;                // 64 KB
    unsigned short* xb  = (unsigned short*)w; w += (size_t)N_NODES * IN_DIM * 2;          // 16 MB
    unsigned short* xlr = (unsigned short*)w; w += (size_t)N_NODES * IN_DIM * 2;          // 16 MB
    unsigned short* hb  = (unsigned short*)w; w += (size_t)N_NODES * HID * 2;             // 8 MB
    unsigned short* T   = (unsigned short*)w; w += (size_t)N_NODES * HEADS * HID * 2;     // 32 MB
    unsigned short* bt1 = (unsigned short*)w; w += (size_t)(2 * HID) * IN_DIM * 2;        // 512 KB
    unsigned short* bt2 = (unsigned short*)w; w += (size_t)HID * (HEADS * HID) * 2;       // 512 KB
    int* deg      = (int*)w;   w += (size_t)N_NODES * 4;
    int* row_start= (int*)w;   w += (size_t)(N_NODES + 64) * 4;
    int* pos      = (int*)w;   w += (size_t)N_NODES * 4;
    int* col      = (int*)w;   w += (size_t)N_EDGES * 4;

    // --- weight packing / input conversion ---
    f32_to_bf16_kernel<<<(N_NODES * IN_DIM / 4) / 256, 256, 0, stream>>>(x, xb, N_NODES * IN_DIM);
    pack_wlr_bt_kernel<<<(2 * HID * IN_DIM) / 256, 256, 0, stream>>>(sage_w_l, sage_w_r, bt1);
    pack_wstack_bt_kernel<<<(HID * HEADS * HID) / 256, 256, 0, stream>>>(gat_w, bt2);
    watt_kernel<<<8, 256, 0, stream>>>(gat_w, att_src, att_dst, watt);

    // --- CSR build (by dst) ---
    zero_int_kernel<<<(N_NODES + 255) / 256, 256, 0, stream>>>(deg, N_NODES);
    deg_kernel<<<N_EDGES / 256, 256, 0, stream>>>(ei, deg);
    scan_kernel<<<1, 256, 0, stream>>>(deg, row_start, pos);
    fill_kernel<<<N_EDGES / 256, 256, 0, stream>>>(ei, pos, col);
    zero_f32_kernel<<<(NBATCH * HID) / 256, 256, 0, stream>>>(pooled, NBATCH * HID);

    // --- xlr = x @ [W_l | W_r]  (bf16 MFMA, bf16 output) ---
    gemm_bt_kernel<<<dim3((2 * HID) / BN, N_NODES / BM), 256, 0, stream>>>(
        xb, bt1, nullptr, xlr, N_NODES, 2 * HID, IN_DIM, nullptr, 1.f, 0);

    // --- SAGE mean-agg + h = relu(...) + attention scalars (bf16 gather) ---
    sage_agg_kernel<<<N_NODES / 4, 256, 0, stream>>>(xlr, row_start, col, sage_b_l, watt, hb, a_att);

    // --- GAT softmax + weighted aggregation of h (bf16 gather, writes bf16 T) ---
    gat_agg_kernel<<<N_NODES / 4, 256, 0, stream>>>(hb, a_att, row_start, col, T);

    // --- out_nodes = relu(T @ Wstack * 0.25 + gat_b)  (bf16 MFMA, fp32 output) ---
    gemm_bt_kernel<<<dim3(HID / BN, N_NODES / BM), 256, 0, stream>>>(
        T, bt2, outn, nullptr, N_NODES, HID, HEADS * HID, gat_b, 0.25f, 1);

    // --- global mean pool (2-stage) + action head ---
    pool_partial_kernel<<<N_NODES / 64, 256, 0, stream>>>(outn, batch, pooled);
    head_kernel<<<NBATCH, 256, 0, stream>>>(pooled, batch, head_w, head_b, out);
}

// Round 4
// 302.203 us; speedup vs baseline: 1.9169x; 1.0830x over previous
//
#include <hip/hip_runtime.h>
#include <math.h>

#define N_NODES 16384
#define N_EDGES 262144
#define IN_DIM  512
#define HID     256
#define HEADS   4
#define NBATCH  64
#define ACTIONS 32
#define NEG_SLOPE 0.2f

typedef __attribute__((ext_vector_type(8))) short short8;
typedef __attribute__((ext_vector_type(4))) float f32x4;

__device__ __forceinline__ float lrelu(float v) { return v > 0.f ? v : NEG_SLOPE * v; }

__device__ __forceinline__ unsigned short bf16_rne(float f) {
    union { float f; unsigned int u; } x; x.f = f;
    unsigned int u = x.u;
    unsigned int r = (u + 0x7FFFu + ((u >> 16) & 1u)) >> 16;
    return (unsigned short)r;
}

__device__ __forceinline__ float bf16_to_f32(unsigned short s) {
    union { unsigned int u; float f; } x; x.u = (unsigned int)s << 16;
    return x.f;
}

__device__ __forceinline__ float4 bf4_to_f4(ushort4 u) {
    return make_float4(bf16_to_f32(u.x), bf16_to_f32(u.y), bf16_to_f32(u.z), bf16_to_f32(u.w));
}

__device__ __forceinline__ void async_copy16(const unsigned short* g, unsigned short* l) {
    __builtin_amdgcn_global_load_lds(
        (const __attribute__((address_space(1))) unsigned int*)g,
        (__attribute__((address_space(3))) unsigned int*)l, 16, 0, 0);
}

// ---------------------------------------------------------------- utility
__global__ void zero_int_kernel(int* __restrict__ p, int n) {
    int i = blockIdx.x * 256 + threadIdx.x;
    if (i < n) p[i] = 0;
}

__global__ void zero_f32_kernel(float* __restrict__ p, int n) {
    int i = blockIdx.x * 256 + threadIdx.x;
    if (i < n) p[i] = 0.f;
}

__global__ void f32_to_bf16_kernel(const float* __restrict__ in, unsigned short* __restrict__ out, int n) {
    int i = (blockIdx.x * 256 + threadIdx.x) * 4;
    if (i < n) {
        float4 v = *(const float4*)(in + i);
        ushort4 o;
        o.x = bf16_rne(v.x); o.y = bf16_rne(v.y); o.z = bf16_rne(v.z); o.w = bf16_rne(v.w);
        *(ushort4*)(out + i) = o;
    }
}

// Bt1[j][k] = wlr[k][j]: j<256 -> wl[k][j], else wr[k][j-256].  [512,512] bf16 row-major.
__global__ void pack_wlr_bt_kernel(const float* __restrict__ wl, const float* __restrict__ wr,
                                   unsigned short* __restrict__ bt) {
    int idx = blockIdx.x * 256 + threadIdx.x;
    int j = idx >> 9;
    int k = idx & 511;
    float v = (j < HID) ? wl[k * HID + j] : wr[k * HID + (j - HID)];
    bt[idx] = bf16_rne(v);
}

// Bt2[c][h*256+k] = gat_w[k][h*256+c].  [256,1024] bf16 row-major.
__global__ void pack_wstack_bt_kernel(const float* __restrict__ gat_w, unsigned short* __restrict__ bt) {
    int idx = blockIdx.x * 256 + threadIdx.x;
    int c = idx >> 10;
    int r = idx & 1023;
    int h = r >> 8;
    int k = r & 255;
    bt[idx] = bf16_rne(gat_w[(size_t)k * (HEADS * HID) + h * HID + c]);
}

// watt[j][c]: j<4 -> W_h@att_src_h ; j>=4 -> W_h@att_dst_h  ([8][256] fp32)
__global__ void watt_kernel(const float* __restrict__ gat_w,
                            const float* __restrict__ att_src,
                            const float* __restrict__ att_dst,
                            float* __restrict__ watt) {
    int j = blockIdx.x;
    int c = threadIdx.x;
    int hh = j & 3;
    const float* att = (j < 4) ? (att_src + hh * HID) : (att_dst + hh * HID);
    float s = 0.f;
    for (int cc = 0; cc < HID; cc++)
        s += gat_w[(size_t)c * (HEADS * HID) + hh * HID + cc] * att[cc];
    watt[j * HID + c] = s;
}

// ---------------------------------------------------------------- CSR build
__global__ void deg_kernel(const int* __restrict__ ei, int* __restrict__ deg) {
    int e = blockIdx.x * 256 + threadIdx.x;
    if (e < N_EDGES) atomicAdd(&deg[ei[N_EDGES + e]], 1);
}

__global__ void scan_kernel(const int* __restrict__ deg, int* __restrict__ row_start,
                            int* __restrict__ pos) {
    __shared__ int part[256];
    int t = threadIdx.x;
    int base = t * 64;
    int s = 0;
    for (int i = 0; i < 64; i++) s += deg[base + i];
    part[t] = s;
    __syncthreads();
    if (t == 0) {
        int acc = 0;
        for (int i = 0; i < 256; i++) { int v = part[i]; part[i] = acc; acc += v; }
    }
    __syncthreads();
    int run = part[t];
    for (int i = 0; i < 64; i++) {
        row_start[base + i] = run;
        pos[base + i] = run;
        run += deg[base + i];
    }
    if (t == 255) row_start[N_NODES] = run;
}

__global__ void fill_kernel(const int* __restrict__ ei, int* __restrict__ pos,
                            int* __restrict__ col) {
    int e = blockIdx.x * 256 + threadIdx.x;
    if (e < N_EDGES) {
        int s = ei[e];
        int d = ei[N_EDGES + e];
        int p = atomicAdd(&pos[d], 1);
        col[p] = s;
    }
}

// ---------------------------------------------------------------- bf16 MFMA GEMM (m97 structure)
#define BM 128
#define BN 128
#define BK 32

__global__ __launch_bounds__(256) void gemm_bt_kernel(const unsigned short* __restrict__ A,
                                                      const unsigned short* __restrict__ Bt,
                                                      float* __restrict__ Cf,
                                                      unsigned short* __restrict__ Cb,
                                                      int M, int Nn, int K,
                                                      const float* __restrict__ bias,
                                                      float scale, int mode) {
    __shared__ __align__(16) unsigned short As[BM * BK];
    __shared__ __align__(16) unsigned short Bs[BN * BK];

    int tid  = threadIdx.x;
    int wv   = tid >> 6;
    int lane = tid & 63;
    int m0 = blockIdx.y * BM;
    int n0 = blockIdx.x * BN;
    int wm = (wv & 1) * 64;
    int wn = (wv >> 1) * 64;

    int srow = tid >> 2;
    int scol = (tid & 3) * 8;
    const unsigned short* Ag0 = A  + (size_t)(m0 + srow) * K + scol;
    const unsigned short* Ag1 = A  + (size_t)(m0 + 64 + srow) * K + scol;
    const unsigned short* Bg0 = Bt + (size_t)(n0 + srow) * K + scol;
    const unsigned short* Bg1 = Bt + (size_t)(n0 + 64 + srow) * K + scol;
    unsigned short* Al0 = As + wv * 512;
    unsigned short* Al1 = As + 2048 + wv * 512;
    unsigned short* Bl0 = Bs + wv * 512;
    unsigned short* Bl1 = Bs + 2048 + wv * 512;

    int fr   = lane & 15;
    int fk   = (lane >> 4) * 8;
    f32x4 acc[4][4] = {};

    for (int kt = 0; kt < K; kt += BK) {
        async_copy16(Ag0 + kt, Al0);
        async_copy16(Ag1 + kt, Al1);
        async_copy16(Bg0 + kt, Bl0);
        async_copy16(Bg1 + kt, Bl1);
        __syncthreads();

        short8 af[4], bf[4];
#pragma unroll
        for (int mi = 0; mi < 4; mi++)
            af[mi] = *(const short8*)&As[(wm + mi * 16 + fr) * BK + fk];
#pragma unroll
        for (int ni = 0; ni < 4; ni++)
            bf[ni] = *(const short8*)&Bs[(wn + ni * 16 + fr) * BK + fk];
#pragma unroll
        for (int mi = 0; mi < 4; mi++)
#pragma unroll
            for (int ni = 0; ni < 4; ni++)
                acc[mi][ni] = __builtin_amdgcn_mfma_f32_16x16x32_bf16(af[mi], bf[ni], acc[mi][ni], 0, 0, 0);
        __syncthreads();
    }

    int cr = (lane >> 4) * 4;
    int cc = lane & 15;
#pragma unroll
    for (int mi = 0; mi < 4; mi++) {
#pragma unroll
        for (int ni = 0; ni < 4; ni++) {
            int gc = n0 + wn + ni * 16 + cc;
            float b = (mode == 1) ? bias[gc] : 0.f;
#pragma unroll
            for (int r = 0; r < 4; r++) {
                int gr = m0 + wm + mi * 16 + cr + r;
                float v = acc[mi][ni][r];
                if (mode == 1) {
                    Cf[(size_t)gr * Nn + gc] = fmaxf(fmaf(v, scale, b), 0.f);
                } else {
                    Cb[(size_t)gr * Nn + gc] = bf16_rne(v);
                }
            }
        }
    }
}

// ---------------------------------------------------------------- SAGE aggregation + h + attention scalars
// 4x-unrolled gather: 4 independent row loads in flight per wave.
__global__ __launch_bounds__(256) void sage_agg_kernel(const unsigned short* __restrict__ xlr,
                                                       const int* __restrict__ row_start,
                                                       const int* __restrict__ col,
                                                       const float* __restrict__ b_l,
                                                       const float* __restrict__ watt,
                                                       unsigned short* __restrict__ hb,
                                                       float* __restrict__ a_att) {
    __shared__ float watt_s[8 * HID];
    for (int i = threadIdx.x; i < 8 * HID; i += 256) watt_s[i] = watt[i];
    __syncthreads();

    int wave = threadIdx.x >> 6;
    int lane = threadIdx.x & 63;
    int n = blockIdx.x * 4 + wave;
    int start = row_start[n], end = row_start[n + 1];
    int c0 = lane * 4;

    float4 acc = make_float4(0.f, 0.f, 0.f, 0.f);
    int e = start;
    for (; e + 4 <= end; e += 4) {
        int s0 = col[e], s1 = col[e + 1], s2 = col[e + 2], s3 = col[e + 3];
        ushort4 u0 = *(const ushort4*)(xlr + (size_t)s0 * IN_DIM + c0);
        ushort4 u1 = *(const ushort4*)(xlr + (size_t)s1 * IN_DIM + c0);
        ushort4 u2 = *(const ushort4*)(xlr + (size_t)s2 * IN_DIM + c0);
        ushort4 u3 = *(const ushort4*)(xlr + (size_t)s3 * IN_DIM + c0);
        float4 v0 = bf4_to_f4(u0), v1 = bf4_to_f4(u1), v2 = bf4_to_f4(u2), v3 = bf4_to_f4(u3);
        acc.x += (v0.x + v1.x) + (v2.x + v3.x);
        acc.y += (v0.y + v1.y) + (v2.y + v3.y);
        acc.z += (v0.z + v1.z) + (v2.z + v3.z);
        acc.w += (v0.w + v1.w) + (v2.w + v3.w);
    }
    for (; e < end; e++) {
        int s = col[e];
        float4 v = bf4_to_f4(*(const ushort4*)(xlr + (size_t)s * IN_DIM + c0));
        acc.x += v.x; acc.y += v.y; acc.z += v.z; acc.w += v.w;
    }
    float inv = 1.f / (float)max(end - start, 1);
    float4 xr = bf4_to_f4(*(const ushort4*)(xlr + (size_t)n * IN_DIM + HID + c0));
    float4 bl = *(const float4*)(b_l + c0);
    float4 hv;
    hv.x = fmaxf(fmaf(acc.x, inv, bl.x + xr.x), 0.f);
    hv.y = fmaxf(fmaf(acc.y, inv, bl.y + xr.y), 0.f);
    hv.z = fmaxf(fmaf(acc.z, inv, bl.z + xr.z), 0.f);
    hv.w = fmaxf(fmaf(acc.w, inv, bl.w + xr.w), 0.f);
    ushort4 ho;
    ho.x = bf16_rne(hv.x); ho.y = bf16_rne(hv.y); ho.z = bf16_rne(hv.z); ho.w = bf16_rne(hv.w);
    *(ushort4*)(hb + (size_t)n * HID + c0) = ho;

    float p[8];
#pragma unroll
    for (int j = 0; j < 8; j++) {
        float4 wt = *(const float4*)&watt_s[j * HID + c0];
        p[j] = hv.x * wt.x + hv.y * wt.y + hv.z * wt.z + hv.w * wt.w;
    }
#pragma unroll
    for (int off = 32; off; off >>= 1)
#pragma unroll
        for (int j = 0; j < 8; j++) p[j] += __shfl_down(p[j], off);
    if (lane == 0) {
#pragma unroll
        for (int j = 0; j < 8; j++) a_att[n * 8 + j] = p[j];
    }
}

// ---------------------------------------------------------------- GAT edge-softmax + weighted aggregation
// Weights staged lane-parallel into wave-private LDS (one exp pass per 64 edges),
// aggregation loop 2x-unrolled reading broadcast LDS weights.
__global__ __launch_bounds__(256) void gat_agg_kernel(const unsigned short* __restrict__ hb,
                                                      const float* __restrict__ a_att,
                                                      const int* __restrict__ row_start,
                                                      const int* __restrict__ col,
                                                      unsigned short* __restrict__ T) {
    __shared__ __align__(16) float w_s[4][64 * 4];   // [wave][edge*4+head]
    int wave = threadIdx.x >> 6;
    int lane = threadIdx.x & 63;
    int n = blockIdx.x * 4 + wave;
    int start = row_start[n], end = row_start[n + 1];

    float4 an = *(const float4*)(a_att + n * 8);       // a_src of n
    float4 ad = *(const float4*)(a_att + n * 8 + 4);   // a_dst of n
    float adst[4] = {ad.x, ad.y, ad.z, ad.w};
    float selfl[4], m[4];
    {
        float asn[4] = {an.x, an.y, an.z, an.w};
#pragma unroll
        for (int hh = 0; hh < 4; hh++) {
            selfl[hh] = lrelu(asn[hh] + adst[hh]);
            m[hh] = -INFINITY;
        }
    }
    // pass 1: max over in-edges (lane-strided)
    for (int e = start + lane; e < end; e += 64) {
        int s = col[e];
        float4 as = *(const float4*)(a_att + s * 8);
        m[0] = fmaxf(m[0], lrelu(as.x + adst[0]));
        m[1] = fmaxf(m[1], lrelu(as.y + adst[1]));
        m[2] = fmaxf(m[2], lrelu(as.z + adst[2]));
        m[3] = fmaxf(m[3], lrelu(as.w + adst[3]));
    }
#pragma unroll
    for (int off = 32; off; off >>= 1)
#pragma unroll
        for (int hh = 0; hh < 4; hh++) m[hh] = fmaxf(m[hh], __shfl_down(m[hh], off));
#pragma unroll
    for (int hh = 0; hh < 4; hh++) {
        m[hh] = __shfl(m[hh], 0);
        m[hh] = fmaxf(m[hh], selfl[hh]);
    }
    // pass 2: denom
    float d[4] = {0.f, 0.f, 0.f, 0.f};
    for (int e = start + lane; e < end; e += 64) {
        int s = col[e];
        float4 as = *(const float4*)(a_att + s * 8);
        d[0] += __expf(lrelu(as.x + adst[0]) - m[0]);
        d[1] += __expf(lrelu(as.y + adst[1]) - m[1]);
        d[2] += __expf(lrelu(as.z + adst[2]) - m[2]);
        d[3] += __expf(lrelu(as.w + adst[3]) - m[3]);
    }
#pragma unroll
    for (int off = 32; off; off >>= 1)
#pragma unroll
        for (int hh = 0; hh < 4; hh++) d[hh] += __shfl_down(d[hh], off);
    float invd[4];
#pragma unroll
    for (int hh = 0; hh < 4; hh++) {
        d[hh] = __shfl(d[hh], 0) + __expf(selfl[hh] - m[hh]);
        invd[hh] = 1.f / d[hh];
    }

    // phase B: chunked weight staging + aggregation
    int c0 = lane * 4;
    float4 hn = bf4_to_f4(*(const ushort4*)(hb + (size_t)n * HID + c0));
    float4 acc[4];
#pragma unroll
    for (int hh = 0; hh < 4; hh++) {
        float ws = __expf(selfl[hh] - m[hh]) * invd[hh];
        acc[hh] = make_float4(ws * hn.x, ws * hn.y, ws * hn.z, ws * hn.w);
    }
    for (int base = start; base < end; base += 64) {
        int cnt = min(64, end - base);
        if (lane < cnt) {
            int s = col[base + lane];
            float4 as = *(const float4*)(a_att + s * 8);
            float4 wv;
            wv.x = __expf(lrelu(as.x + adst[0]) - m[0]) * invd[0];
            wv.y = __expf(lrelu(as.y + adst[1]) - m[1]) * invd[1];
            wv.z = __expf(lrelu(as.z + adst[2]) - m[2]) * invd[2];
            wv.w = __expf(lrelu(as.w + adst[3]) - m[3]) * invd[3];
            *(float4*)&w_s[wave][lane * 4] = wv;
        }
        __builtin_amdgcn_wave_barrier();   // wave-private LDS: DS ops are wave-ordered, no block barrier

        int i = 0;
        for (; i + 2 <= cnt; i += 2) {
            int s0 = col[base + i], s1 = col[base + i + 1];
            float4 w0 = *(const float4*)&w_s[wave][i * 4];
            float4 w1 = *(const float4*)&w_s[wave][(i + 1) * 4];
            ushort4 u0 = *(const ushort4*)(hb + (size_t)s0 * HID + c0);
            ushort4 u1 = *(const ushort4*)(hb + (size_t)s1 * HID + c0);
            float4 h0 = bf4_to_f4(u0), h1 = bf4_to_f4(u1);
            float wr0[4] = {w0.x, w0.y, w0.z, w0.w};
            float wr1[4] = {w1.x, w1.y, w1.z, w1.w};
#pragma unroll
            for (int hh = 0; hh < 4; hh++) {
                acc[hh].x = fmaf(wr0[hh], h0.x, fmaf(wr1[hh], h1.x, acc[hh].x));
                acc[hh].y = fmaf(wr0[hh], h0.y, fmaf(wr1[hh], h1.y, acc[hh].y));
                acc[hh].z = fmaf(wr0[hh], h0.z, fmaf(wr1[hh], h1.z, acc[hh].z));
                acc[hh].w = fmaf(wr0[hh], h0.w, fmaf(wr1[hh], h1.w, acc[hh].w));
            }
        }
        if (i < cnt) {
            int s0 = col[base + i];
            float4 w0 = *(const float4*)&w_s[wave][i * 4];
            float4 h0 = bf4_to_f4(*(const ushort4*)(hb + (size_t)s0 * HID + c0));
            float wr0[4] = {w0.x, w0.y, w0.z, w0.w};
#pragma unroll
            for (int hh = 0; hh < 4; hh++) {
                acc[hh].x = fmaf(wr0[hh], h0.x, acc[hh].x);
                acc[hh].y = fmaf(wr0[hh], h0.y, acc[hh].y);
                acc[hh].z = fmaf(wr0[hh], h0.z, acc[hh].z);
                acc[hh].w = fmaf(wr0[hh], h0.w, acc[hh].w);
            }
        }
        __builtin_amdgcn_wave_barrier();
    }
#pragma unroll
    for (int hh = 0; hh < 4; hh++) {
        ushort4 o;
        o.x = bf16_rne(acc[hh].x); o.y = bf16_rne(acc[hh].y);
        o.z = bf16_rne(acc[hh].z); o.w = bf16_rne(acc[hh].w);
        *(ushort4*)(T + (size_t)n * (HEADS * HID) + hh * HID + c0) = o;
    }
}

// ---------------------------------------------------------------- pool: partial sums + head
__global__ __launch_bounds__(256) void pool_partial_kernel(const float* __restrict__ outn,
                                                           const int* __restrict__ batch,
                                                           float* __restrict__ pooled) {
    int c = threadIdx.x;
    int n0 = blockIdx.x * 64;
    int cur = batch[n0];
    float acc = 0.f;
    for (int i = 0; i < 64; i++) {
        int n = n0 + i;
        int b = batch[n];
        if (b != cur) {
            atomicAdd(&pooled[cur * HID + c], acc);
            acc = 0.f;
            cur = b;
        }
        acc += outn[(size_t)n * HID + c];
    }
    atomicAdd(&pooled[cur * HID + c], acc);
}

__device__ __forceinline__ int lower_bound_i(const int* a, int n, int v) {
    int lo = 0, hi = n;
    while (lo < hi) {
        int mid = (lo + hi) >> 1;
        if (a[mid] < v) lo = mid + 1; else hi = mid;
    }
    return lo;
}

__global__ __launch_bounds__(256) void head_kernel(const float* __restrict__ pooled,
                                                   const int* __restrict__ batch,
                                                   const float* __restrict__ head_w,
                                                   const float* __restrict__ head_b,
                                                   float* __restrict__ out) {
    __shared__ float sm[HID];
    int b = blockIdx.x;
    int c = threadIdx.x;
    int lo = lower_bound_i(batch, N_NODES, b);
    int hi = lower_bound_i(batch, N_NODES, b + 1);
    int cnt = hi - lo;
    sm[c] = pooled[b * HID + c] / (float)max(cnt, 1);
    __syncthreads();
    if (c < ACTIONS) {
        float acc = head_b[c];
        for (int k = 0; k < HID; k++) acc = fmaf(sm[k], head_w[k * ACTIONS + c], acc);
        out[b * ACTIONS + c] = acc;
    }
}

// ---------------------------------------------------------------- launcher
extern "C" void kernel_launch(void* const* d_in, const int* in_sizes, int n_in,
                              void* d_out, int out_size, void* d_ws, size_t ws_size,
                              hipStream_t stream) {
    const float* x        = (const float*)d_in[0];
    const int*   ei       = (const int*)d_in[1];
    const int*   batch    = (const int*)d_in[2];
    const float* sage_w_l = (const float*)d_in[3];
    const float* sage_b_l = (const float*)d_in[4];
    const float* sage_w_r = (const float*)d_in[5];
    const float* gat_w    = (const float*)d_in[6];
    const float* att_src  = (const float*)d_in[7];
    const float* att_dst  = (const float*)d_in[8];
    const float* gat_b    = (const float*)d_in[9];
    const float* head_w   = (const float*)d_in[10];
    const float* head_b   = (const float*)d_in[11];
    float* out = (float*)d_out;

    char* w = (char*)d_ws;
    float* outn   = (float*)w; w += (size_t)N_NODES * HID * 4;
    float* a_att  = (float*)w; w += (size_t)N_NODES * 8 * 4;
    float* watt   = (float*)w; w += (size_t)8 * HID * 4;
    float* pooled = (float*)w; w += (size_t)NBATCH * HID * 4;
    unsigned short* xb  = (unsigned short*)w; w += (size_t)N_NODES * IN_DIM * 2;
    unsigned short* xlr = (unsigned short*)w; w += (size_t)N_NODES * IN_DIM * 2;
    unsigned short* hb  = (unsigned short*)w; w += (size_t)N_NODES * HID * 2;
    unsigned short* T   = (unsigned short*)w; w += (size_t)N_NODES * HEADS * HID * 2;
    unsigned short* bt1 = (unsigned short*)w; w += (size_t)(2 * HID) * IN_DIM * 2;
    unsigned short* bt2 = (unsigned short*)w; w += (size_t)HID * (HEADS * HID) * 2;
    int* deg      = (int*)w;   w += (size_t)N_NODES * 4;
    int* row_start= (int*)w;   w += (size_t)(N_NODES + 64) * 4;
    int* pos      = (int*)w;   w += (size_t)N_NODES * 4;
    int* col      = (int*)w;   w += (size_t)N_EDGES * 4;

    f32_to_bf16_kernel<<<(N_NODES * IN_DIM / 4) / 256, 256, 0, stream>>>(x, xb, N_NODES * IN_DIM);
    pack_wlr_bt_kernel<<<(2 * HID * IN_DIM) / 256, 256, 0, stream>>>(sage_w_l, sage_w_r, bt1);
    pack_wstack_bt_kernel<<<(HID * HEADS * HID) / 256, 256, 0, stream>>>(gat_w, bt2);
    watt_kernel<<<8, 256, 0, stream>>>(gat_w, att_src, att_dst, watt);

    zero_int_kernel<<<(N_NODES + 255) / 256, 256, 0, stream>>>(deg, N_NODES);
    deg_kernel<<<N_EDGES / 256, 256, 0, stream>>>(ei, deg);
    scan_kernel<<<1, 256, 0, stream>>>(deg, row_start, pos);
    fill_kernel<<<N_EDGES / 256, 256, 0, stream>>>(ei, pos, col);
    zero_f32_kernel<<<(NBATCH * HID) / 256, 256, 0, stream>>>(pooled, NBATCH * HID);

    gemm_bt_kernel<<<dim3((2 * HID) / BN, N_NODES / BM), 256, 0, stream>>>(
        xb, bt1, nullptr, xlr, N_NODES, 2 * HID, IN_DIM, nullptr, 1.f, 0);

    sage_agg_kernel<<<N_NODES / 4, 256, 0, stream>>>(xlr, row_start, col, sage_b_l, watt, hb, a_att);

    gat_agg_kernel<<<N_NODES / 4, 256, 0, stream>>>(hb, a_att, row_start, col, T);

    gemm_bt_kernel<<<dim3(HID / BN, N_NODES / BM), 256, 0, stream>>>(
        T, bt2, outn, nullptr, N_NODES, HID, HEADS * HID, gat_b, 0.25f, 1);

    pool_partial_kernel<<<N_NODES / 64, 256, 0, stream>>>(outn, batch, pooled);
    head_kernel<<<NBATCH, 256, 0, stream>>>(pooled, batch, head_w, head_b, out);
}

// Round 5
// 262.382 us; speedup vs baseline: 2.2078x; 1.1518x over previous
//
#include <hip/hip_runtime.h>
#include <math.h>

#define N_NODES 16384
#define N_EDGES 262144
#define IN_DIM  512
#define HID     256
#define HEADS   4
#define NBATCH  64
#define ACTIONS 32
#define NEG_SLOPE 0.2f

typedef __attribute__((ext_vector_type(8))) short short8;
typedef __attribute__((ext_vector_type(4))) float f32x4;

__device__ __forceinline__ float lrelu(float v) { return v > 0.f ? v : NEG_SLOPE * v; }

__device__ __forceinline__ unsigned short bf16_rne(float f) {
    union { float f; unsigned int u; } x; x.f = f;
    unsigned int u = x.u;
    unsigned int r = (u + 0x7FFFu + ((u >> 16) & 1u)) >> 16;
    return (unsigned short)r;
}

__device__ __forceinline__ float bf16_to_f32(unsigned short s) {
    union { unsigned int u; float f; } x; x.u = (unsigned int)s << 16;
    return x.f;
}

__device__ __forceinline__ float4 bf4_to_f4(ushort4 u) {
    return make_float4(bf16_to_f32(u.x), bf16_to_f32(u.y), bf16_to_f32(u.z), bf16_to_f32(u.w));
}

__device__ __forceinline__ void async_copy16(const unsigned short* g, unsigned short* l) {
    __builtin_amdgcn_global_load_lds(
        (const __attribute__((address_space(1))) unsigned int*)g,
        (__attribute__((address_space(3))) unsigned int*)l, 16, 0, 0);
}

// ---------------------------------------------------------------- fused setup
// block ranges: [0,8192) x->bf16 | [8192,9216) pack wlr | [9216,10240) pack wstack
//               [10240,10248) watt | [10248,10376) zero deg+pooled
#define NB_CONV 8192
#define NB_WLR  1024
#define NB_WSTK 1024
#define NB_WATT 8
#define NB_ZERO 128
#define NB_SETUP (NB_CONV + NB_WLR + NB_WSTK + NB_WATT + NB_ZERO)

__global__ __launch_bounds__(256) void setup_kernel(
        const float* __restrict__ x, unsigned short* __restrict__ xb,
        const float* __restrict__ wl, const float* __restrict__ wr, unsigned short* __restrict__ bt1,
        const float* __restrict__ gat_w, unsigned short* __restrict__ bt2,
        const float* __restrict__ att_src, const float* __restrict__ att_dst, float* __restrict__ watt,
        int* __restrict__ deg, float* __restrict__ pooled) {
    int bid = blockIdx.x, tid = threadIdx.x;
    if (bid < NB_CONV) {
        int i = (bid * 256 + tid) * 4;
        float4 v = *(const float4*)(x + i);
        ushort4 o;
        o.x = bf16_rne(v.x); o.y = bf16_rne(v.y); o.z = bf16_rne(v.z); o.w = bf16_rne(v.w);
        *(ushort4*)(xb + i) = o;
    } else if (bid < NB_CONV + NB_WLR) {
        // bt1[j][k] = (j<256 ? wl[k][j] : wr[k][j-256]);  j in [0,512), k in [0,512)
        int idx = (bid - NB_CONV) * 256 + tid;
        int j = idx >> 9;
        int k = idx & 511;
        float v = (j < HID) ? wl[k * HID + j] : wr[k * HID + (j - HID)];
        bt1[idx] = bf16_rne(v);
    } else if (bid < NB_CONV + NB_WLR + NB_WSTK) {
        // bt2[c][h*256+k] = gat_w[k][h*256+c]
        int idx = (bid - NB_CONV - NB_WLR) * 256 + tid;
        int c = idx >> 10;
        int r = idx & 1023;
        int h = r >> 8;
        int k = r & 255;
        bt2[idx] = bf16_rne(gat_w[(size_t)k * (HEADS * HID) + h * HID + c]);
    } else if (bid < NB_CONV + NB_WLR + NB_WSTK + NB_WATT) {
        int j = bid - NB_CONV - NB_WLR - NB_WSTK;   // 0..7
        int c = tid;                                 // 0..255
        int hh = j & 3;
        const float* att = (j < 4) ? (att_src + hh * HID) : (att_dst + hh * HID);
        float s = 0.f;
        for (int cc = 0; cc < HID; cc++)
            s += gat_w[(size_t)c * (HEADS * HID) + hh * HID + cc] * att[cc];
        watt[j * HID + c] = s;
    } else {
        int idx = (bid - NB_CONV - NB_WLR - NB_WSTK - NB_WATT) * 256 + tid;  // 0..32767
        if (idx < N_NODES) deg[idx] = 0;
        else pooled[idx - N_NODES] = 0.f;
    }
}

// ---------------------------------------------------------------- CSR build
__global__ void deg_kernel(const int* __restrict__ ei, int* __restrict__ deg) {
    int e = blockIdx.x * 256 + threadIdx.x;
    if (e < N_EDGES) atomicAdd(&deg[ei[N_EDGES + e]], 1);
}

// 1 block, 256 threads; int4 loads + shfl prefix.
__global__ __launch_bounds__(256) void scan_kernel(const int* __restrict__ deg,
                                                   int* __restrict__ row_start,
                                                   int* __restrict__ pos) {
    int t = threadIdx.x;
    int lane = t & 63, wv = t >> 6;
    int base = t * 64;
    int4 buf[16];
    int sum = 0;
#pragma unroll
    for (int i = 0; i < 16; i++) {
        buf[i] = ((const int4*)(deg + base))[i];
        sum += buf[i].x + buf[i].y + buf[i].z + buf[i].w;
    }
    // inclusive shfl scan within wave
    int v = sum;
#pragma unroll
    for (int off = 1; off < 64; off <<= 1) {
        int u = __shfl_up(v, off);
        if (lane >= off) v += u;
    }
    __shared__ int wsum[4];
    if (lane == 63) wsum[wv] = v;
    __syncthreads();
    int wbase = 0;
    for (int w0 = 0; w0 < wv; w0++) wbase += wsum[w0];
    int run = wbase + v - sum;   // exclusive prefix for this thread's 64 nodes
#pragma unroll
    for (int i = 0; i < 16; i++) {
        int4 b = buf[i];
        int4 o;
        o.x = run; run += b.x;
        o.y = run; run += b.y;
        o.z = run; run += b.z;
        o.w = run; run += b.w;
        ((int4*)(row_start + base))[i] = o;
        ((int4*)(pos + base))[i] = o;
    }
    if (t == 255) row_start[N_NODES] = run;
}

__global__ void fill_kernel(const int* __restrict__ ei, int* __restrict__ pos,
                            int* __restrict__ col) {
    int e = blockIdx.x * 256 + threadIdx.x;
    if (e < N_EDGES) {
        int s = ei[e];
        int d = ei[N_EDGES + e];
        int p = atomicAdd(&pos[d], 1);
        col[p] = s;
    }
}

// ---------------------------------------------------------------- bf16 MFMA GEMM (m97 structure), bf16 out
#define BM 128
#define BN 128
#define BK 32

__global__ __launch_bounds__(256) void gemm_bt_kernel(const unsigned short* __restrict__ A,
                                                      const unsigned short* __restrict__ Bt,
                                                      unsigned short* __restrict__ Cb,
                                                      int Nn, int K) {
    __shared__ __align__(16) unsigned short As[BM * BK];
    __shared__ __align__(16) unsigned short Bs[BN * BK];

    int tid  = threadIdx.x;
    int wv   = tid >> 6;
    int lane = tid & 63;
    int m0 = blockIdx.y * BM;
    int n0 = blockIdx.x * BN;
    int wm = (wv & 1) * 64;
    int wn = (wv >> 1) * 64;

    int srow = tid >> 2;
    int scol = (tid & 3) * 8;
    const unsigned short* Ag0 = A  + (size_t)(m0 + srow) * K + scol;
    const unsigned short* Ag1 = A  + (size_t)(m0 + 64 + srow) * K + scol;
    const unsigned short* Bg0 = Bt + (size_t)(n0 + srow) * K + scol;
    const unsigned short* Bg1 = Bt + (size_t)(n0 + 64 + srow) * K + scol;
    unsigned short* Al0 = As + wv * 512;
    unsigned short* Al1 = As + 2048 + wv * 512;
    unsigned short* Bl0 = Bs + wv * 512;
    unsigned short* Bl1 = Bs + 2048 + wv * 512;

    int fr = lane & 15;
    int fk = (lane >> 4) * 8;
    f32x4 acc[4][4] = {};

    for (int kt = 0; kt < K; kt += BK) {
        async_copy16(Ag0 + kt, Al0);
        async_copy16(Ag1 + kt, Al1);
        async_copy16(Bg0 + kt, Bl0);
        async_copy16(Bg1 + kt, Bl1);
        __syncthreads();

        short8 af[4], bf[4];
#pragma unroll
        for (int mi = 0; mi < 4; mi++)
            af[mi] = *(const short8*)&As[(wm + mi * 16 + fr) * BK + fk];
#pragma unroll
        for (int ni = 0; ni < 4; ni++)
            bf[ni] = *(const short8*)&Bs[(wn + ni * 16 + fr) * BK + fk];
#pragma unroll
        for (int mi = 0; mi < 4; mi++)
#pragma unroll
            for (int ni = 0; ni < 4; ni++)
                acc[mi][ni] = __builtin_amdgcn_mfma_f32_16x16x32_bf16(af[mi], bf[ni], acc[mi][ni], 0, 0, 0);
        __syncthreads();
    }

    int cr = (lane >> 4) * 4;
    int cc = lane & 15;
#pragma unroll
    for (int mi = 0; mi < 4; mi++) {
#pragma unroll
        for (int ni = 0; ni < 4; ni++) {
            int gc = n0 + wn + ni * 16 + cc;
#pragma unroll
            for (int r = 0; r < 4; r++) {
                int gr = m0 + wm + mi * 16 + cr + r;
                Cb[(size_t)gr * Nn + gc] = bf16_rne(acc[mi][ni][r]);
            }
        }
    }
}

// ---------------------------------------------------------------- GEMM2 fused with mean-pool partial sums
// pooled[batch[m]][n] += relu(sum_k A[m][k]*Bt[n][k] * scale + bias[n])
__global__ __launch_bounds__(256) void gemm_bt_pool_kernel(const unsigned short* __restrict__ A,
                                                           const unsigned short* __restrict__ Bt,
                                                           const int* __restrict__ batch,
                                                           const float* __restrict__ bias,
                                                           float scale,
                                                           float* __restrict__ pooled,
                                                           int Nn, int K) {
    __shared__ __align__(16) unsigned short As[BM * BK];
    __shared__ __align__(16) unsigned short Bs[BN * BK];
    __shared__ int bsh[BM];

    int tid  = threadIdx.x;
    int wv   = tid >> 6;
    int lane = tid & 63;
    int m0 = blockIdx.y * BM;
    int n0 = blockIdx.x * BN;
    int wm = (wv & 1) * 64;
    int wn = (wv >> 1) * 64;

    if (tid < BM) bsh[tid] = batch[m0 + tid];

    int srow = tid >> 2;
    int scol = (tid & 3) * 8;
    const unsigned short* Ag0 = A  + (size_t)(m0 + srow) * K + scol;
    const unsigned short* Ag1 = A  + (size_t)(m0 + 64 + srow) * K + scol;
    const unsigned short* Bg0 = Bt + (size_t)(n0 + srow) * K + scol;
    const unsigned short* Bg1 = Bt + (size_t)(n0 + 64 + srow) * K + scol;
    unsigned short* Al0 = As + wv * 512;
    unsigned short* Al1 = As + 2048 + wv * 512;
    unsigned short* Bl0 = Bs + wv * 512;
    unsigned short* Bl1 = Bs + 2048 + wv * 512;

    int fr = lane & 15;
    int fk = (lane >> 4) * 8;
    f32x4 acc[4][4] = {};

    for (int kt = 0; kt < K; kt += BK) {
        async_copy16(Ag0 + kt, Al0);
        async_copy16(Ag1 + kt, Al1);
        async_copy16(Bg0 + kt, Bl0);
        async_copy16(Bg1 + kt, Bl1);
        __syncthreads();

        short8 af[4], bf[4];
#pragma unroll
        for (int mi = 0; mi < 4; mi++)
            af[mi] = *(const short8*)&As[(wm + mi * 16 + fr) * BK + fk];
#pragma unroll
        for (int ni = 0; ni < 4; ni++)
            bf[ni] = *(const short8*)&Bs[(wn + ni * 16 + fr) * BK + fk];
#pragma unroll
        for (int mi = 0; mi < 4; mi++)
#pragma unroll
            for (int ni = 0; ni < 4; ni++)
                acc[mi][ni] = __builtin_amdgcn_mfma_f32_16x16x32_bf16(af[mi], bf[ni], acc[mi][ni], 0, 0, 0);
        __syncthreads();
    }

    int cr = (lane >> 4) * 4;
    int cc = lane & 15;
#pragma unroll
    for (int mi = 0; mi < 4; mi++) {
        int rowb = wm + mi * 16 + cr;
        int b0 = bsh[rowb], b3 = bsh[rowb + 3];
#pragma unroll
        for (int ni = 0; ni < 4; ni++) {
            int gc = n0 + wn + ni * 16 + cc;
            float b = bias[gc];
            float v0 = fmaxf(fmaf(acc[mi][ni][0], scale, b), 0.f);
            float v1 = fmaxf(fmaf(acc[mi][ni][1], scale, b), 0.f);
            float v2 = fmaxf(fmaf(acc[mi][ni][2], scale, b), 0.f);
            float v3 = fmaxf(fmaf(acc[mi][ni][3], scale, b), 0.f);
            if (b0 == b3) {
                atomicAdd(&pooled[b0 * HID + gc], (v0 + v1) + (v2 + v3));
            } else {
                atomicAdd(&pooled[bsh[rowb + 0] * HID + gc], v0);
                atomicAdd(&pooled[bsh[rowb + 1] * HID + gc], v1);
                atomicAdd(&pooled[bsh[rowb + 2] * HID + gc], v2);
                atomicAdd(&pooled[bsh[rowb + 3] * HID + gc], v3);
            }
        }
    }
}

// ---------------------------------------------------------------- SAGE aggregation + h + attention scalars
__global__ __launch_bounds__(256) void sage_agg_kernel(const unsigned short* __restrict__ xlr,
                                                       const int* __restrict__ row_start,
                                                       const int* __restrict__ col,
                                                       const float* __restrict__ b_l,
                                                       const float* __restrict__ watt,
                                                       unsigned short* __restrict__ hb,
                                                       float* __restrict__ a_att) {
    __shared__ float watt_s[8 * HID];
    for (int i = threadIdx.x; i < 8 * HID; i += 256) watt_s[i] = watt[i];
    __syncthreads();

    int wave = threadIdx.x >> 6;
    int lane = threadIdx.x & 63;
    int n = blockIdx.x * 4 + wave;
    int start = row_start[n], end = row_start[n + 1];
    int c0 = lane * 4;

    float4 acc = make_float4(0.f, 0.f, 0.f, 0.f);
    int e = start;
    for (; e + 4 <= end; e += 4) {
        int s0 = col[e], s1 = col[e + 1], s2 = col[e + 2], s3 = col[e + 3];
        ushort4 u0 = *(const ushort4*)(xlr + (size_t)s0 * IN_DIM + c0);
        ushort4 u1 = *(const ushort4*)(xlr + (size_t)s1 * IN_DIM + c0);
        ushort4 u2 = *(const ushort4*)(xlr + (size_t)s2 * IN_DIM + c0);
        ushort4 u3 = *(const ushort4*)(xlr + (size_t)s3 * IN_DIM + c0);
        float4 v0 = bf4_to_f4(u0), v1 = bf4_to_f4(u1), v2 = bf4_to_f4(u2), v3 = bf4_to_f4(u3);
        acc.x += (v0.x + v1.x) + (v2.x + v3.x);
        acc.y += (v0.y + v1.y) + (v2.y + v3.y);
        acc.z += (v0.z + v1.z) + (v2.z + v3.z);
        acc.w += (v0.w + v1.w) + (v2.w + v3.w);
    }
    for (; e < end; e++) {
        int s = col[e];
        float4 v = bf4_to_f4(*(const ushort4*)(xlr + (size_t)s * IN_DIM + c0));
        acc.x += v.x; acc.y += v.y; acc.z += v.z; acc.w += v.w;
    }
    float inv = 1.f / (float)max(end - start, 1);
    float4 xr = bf4_to_f4(*(const ushort4*)(xlr + (size_t)n * IN_DIM + HID + c0));
    float4 bl = *(const float4*)(b_l + c0);
    float4 hv;
    hv.x = fmaxf(fmaf(acc.x, inv, bl.x + xr.x), 0.f);
    hv.y = fmaxf(fmaf(acc.y, inv, bl.y + xr.y), 0.f);
    hv.z = fmaxf(fmaf(acc.z, inv, bl.z + xr.z), 0.f);
    hv.w = fmaxf(fmaf(acc.w, inv, bl.w + xr.w), 0.f);
    ushort4 ho;
    ho.x = bf16_rne(hv.x); ho.y = bf16_rne(hv.y); ho.z = bf16_rne(hv.z); ho.w = bf16_rne(hv.w);
    *(ushort4*)(hb + (size_t)n * HID + c0) = ho;

    float p[8];
#pragma unroll
    for (int j = 0; j < 8; j++) {
        float4 wt = *(const float4*)&watt_s[j * HID + c0];
        p[j] = hv.x * wt.x + hv.y * wt.y + hv.z * wt.z + hv.w * wt.w;
    }
#pragma unroll
    for (int off = 32; off; off >>= 1)
#pragma unroll
        for (int j = 0; j < 8; j++) p[j] += __shfl_down(p[j], off);
    if (lane == 0) {
#pragma unroll
        for (int j = 0; j < 8; j++) a_att[n * 8 + j] = p[j];
    }
}

// ---------------------------------------------------------------- GAT: single-sweep edge softmax + aggregation
// Normalization commutes with the sum: T = (sum_e w~_e h_e + w~_self h_n) / (sum w~).
// Shift m = max(selfl, 0) is a free bound (logits ~N(0,1); no overflow risk).
__global__ __launch_bounds__(256) void gat_agg_kernel(const unsigned short* __restrict__ hb,
                                                      const float* __restrict__ a_att,
                                                      const int* __restrict__ row_start,
                                                      const int* __restrict__ col,
                                                      unsigned short* __restrict__ T) {
    __shared__ __align__(16) float w_s[4][64 * 4];   // [wave][edge*4+head]
    int wave = threadIdx.x >> 6;
    int lane = threadIdx.x & 63;
    int n = blockIdx.x * 4 + wave;
    int start = row_start[n], end = row_start[n + 1];

    float4 an = *(const float4*)(a_att + n * 8);
    float4 ad = *(const float4*)(a_att + n * 8 + 4);
    float adst[4] = {ad.x, ad.y, ad.z, ad.w};
    float selfl[4] = {lrelu(an.x + ad.x), lrelu(an.y + ad.y), lrelu(an.z + ad.z), lrelu(an.w + ad.w)};
    float m[4], wself[4];
#pragma unroll
    for (int hh = 0; hh < 4; hh++) {
        m[hh] = fmaxf(selfl[hh], 0.f);
        wself[hh] = __expf(selfl[hh] - m[hh]);
    }

    int c0 = lane * 4;
    float4 hn = bf4_to_f4(*(const ushort4*)(hb + (size_t)n * HID + c0));
    float4 acc[4];
#pragma unroll
    for (int hh = 0; hh < 4; hh++)
        acc[hh] = make_float4(wself[hh] * hn.x, wself[hh] * hn.y, wself[hh] * hn.z, wself[hh] * hn.w);

    float dpart[4] = {0.f, 0.f, 0.f, 0.f};   // lane-partial denominator

    for (int base = start; base < end; base += 64) {
        int cnt = min(64, end - base);
        if (lane < cnt) {
            int s = col[base + lane];
            float4 as = *(const float4*)(a_att + s * 8);
            float4 wv;
            wv.x = __expf(lrelu(as.x + adst[0]) - m[0]);
            wv.y = __expf(lrelu(as.y + adst[1]) - m[1]);
            wv.z = __expf(lrelu(as.z + adst[2]) - m[2]);
            wv.w = __expf(lrelu(as.w + adst[3]) - m[3]);
            *(float4*)&w_s[wave][lane * 4] = wv;
            dpart[0] += wv.x; dpart[1] += wv.y; dpart[2] += wv.z; dpart[3] += wv.w;
        }
        __builtin_amdgcn_wave_barrier();   // wave-private LDS, DS ops wave-ordered

        int i = 0;
        for (; i + 2 <= cnt; i += 2) {
            int s0 = col[base + i], s1 = col[base + i + 1];
            float4 w0 = *(const float4*)&w_s[wave][i * 4];
            float4 w1 = *(const float4*)&w_s[wave][(i + 1) * 4];
            ushort4 u0 = *(const ushort4*)(hb + (size_t)s0 * HID + c0);
            ushort4 u1 = *(const ushort4*)(hb + (size_t)s1 * HID + c0);
            float4 h0 = bf4_to_f4(u0), h1 = bf4_to_f4(u1);
            float wr0[4] = {w0.x, w0.y, w0.z, w0.w};
            float wr1[4] = {w1.x, w1.y, w1.z, w1.w};
#pragma unroll
            for (int hh = 0; hh < 4; hh++) {
                acc[hh].x = fmaf(wr0[hh], h0.x, fmaf(wr1[hh], h1.x, acc[hh].x));
                acc[hh].y = fmaf(wr0[hh], h0.y, fmaf(wr1[hh], h1.y, acc[hh].y));
                acc[hh].z = fmaf(wr0[hh], h0.z, fmaf(wr1[hh], h1.z, acc[hh].z));
                acc[hh].w = fmaf(wr0[hh], h0.w, fmaf(wr1[hh], h1.w, acc[hh].w));
            }
        }
        if (i < cnt) {
            int s0 = col[base + i];
            float4 w0 = *(const float4*)&w_s[wave][i * 4];
            float4 h0 = bf4_to_f4(*(const ushort4*)(hb + (size_t)s0 * HID + c0));
            float wr0[4] = {w0.x, w0.y, w0.z, w0.w};
#pragma unroll
            for (int hh = 0; hh < 4; hh++) {
                acc[hh].x = fmaf(wr0[hh], h0.x, acc[hh].x);
                acc[hh].y = fmaf(wr0[hh], h0.y, acc[hh].y);
                acc[hh].z = fmaf(wr0[hh], h0.z, acc[hh].z);
                acc[hh].w = fmaf(wr0[hh], h0.w, acc[hh].w);
            }
        }
        __builtin_amdgcn_wave_barrier();
    }

    // reduce denominator across lanes, add self, normalize at write-out
#pragma unroll
    for (int off = 32; off; off >>= 1)
#pragma unroll
        for (int hh = 0; hh < 4; hh++) dpart[hh] += __shfl_down(dpart[hh], off);
    float invd[4];
#pragma unroll
    for (int hh = 0; hh < 4; hh++)
        invd[hh] = 1.f / (__shfl(dpart[hh], 0) + wself[hh]);

#pragma unroll
    for (int hh = 0; hh < 4; hh++) {
        ushort4 o;
        o.x = bf16_rne(acc[hh].x * invd[hh]); o.y = bf16_rne(acc[hh].y * invd[hh]);
        o.z = bf16_rne(acc[hh].z * invd[hh]); o.w = bf16_rne(acc[hh].w * invd[hh]);
        *(ushort4*)(T + (size_t)n * (HEADS * HID) + hh * HID + c0) = o;
    }
}

// ---------------------------------------------------------------- head
__device__ __forceinline__ int lower_bound_i(const int* a, int n, int v) {
    int lo = 0, hi = n;
    while (lo < hi) {
        int mid = (lo + hi) >> 1;
        if (a[mid] < v) lo = mid + 1; else hi = mid;
    }
    return lo;
}

__global__ __launch_bounds__(256) void head_kernel(const float* __restrict__ pooled,
                                                   const int* __restrict__ batch,
                                                   const float* __restrict__ head_w,
                                                   const float* __restrict__ head_b,
                                                   float* __restrict__ out) {
    __shared__ float sm[HID];
    int b = blockIdx.x;
    int c = threadIdx.x;
    int lo = lower_bound_i(batch, N_NODES, b);
    int hi = lower_bound_i(batch, N_NODES, b + 1);
    int cnt = hi - lo;
    sm[c] = pooled[b * HID + c] / (float)max(cnt, 1);
    __syncthreads();
    if (c < ACTIONS) {
        float acc = head_b[c];
        for (int k = 0; k < HID; k++) acc = fmaf(sm[k], head_w[k * ACTIONS + c], acc);
        out[b * ACTIONS + c] = acc;
    }
}

// ---------------------------------------------------------------- launcher
extern "C" void kernel_launch(void* const* d_in, const int* in_sizes, int n_in,
                              void* d_out, int out_size, void* d_ws, size_t ws_size,
                              hipStream_t stream) {
    const float* x        = (const float*)d_in[0];
    const int*   ei       = (const int*)d_in[1];
    const int*   batch    = (const int*)d_in[2];
    const float* sage_w_l = (const float*)d_in[3];
    const float* sage_b_l = (const float*)d_in[4];
    const float* sage_w_r = (const float*)d_in[5];
    const float* gat_w    = (const float*)d_in[6];
    const float* att_src  = (const float*)d_in[7];
    const float* att_dst  = (const float*)d_in[8];
    const float* gat_b    = (const float*)d_in[9];
    const float* head_w   = (const float*)d_in[10];
    const float* head_b   = (const float*)d_in[11];
    float* out = (float*)d_out;

    char* w = (char*)d_ws;
    float* a_att  = (float*)w; w += (size_t)N_NODES * 8 * 4;
    float* watt   = (float*)w; w += (size_t)8 * HID * 4;
    float* pooled = (float*)w; w += (size_t)NBATCH * HID * 4;
    unsigned short* xb  = (unsigned short*)w; w += (size_t)N_NODES * IN_DIM * 2;
    unsigned short* xlr = (unsigned short*)w; w += (size_t)N_NODES * IN_DIM * 2;
    unsigned short* hb  = (unsigned short*)w; w += (size_t)N_NODES * HID * 2;
    unsigned short* T   = (unsigned short*)w; w += (size_t)N_NODES * HEADS * HID * 2;
    unsigned short* bt1 = (unsigned short*)w; w += (size_t)(2 * HID) * IN_DIM * 2;
    unsigned short* bt2 = (unsigned short*)w; w += (size_t)HID * (HEADS * HID) * 2;
    int* deg      = (int*)w;   w += (size_t)N_NODES * 4;
    int* row_start= (int*)w;   w += (size_t)(N_NODES + 64) * 4;
    int* pos      = (int*)w;   w += (size_t)N_NODES * 4;
    int* col      = (int*)w;   w += (size_t)N_EDGES * 4;

    // fused prologue: convert + pack + watt + zero deg/pooled
    setup_kernel<<<NB_SETUP, 256, 0, stream>>>(x, xb, sage_w_l, sage_w_r, bt1,
                                               gat_w, bt2, att_src, att_dst, watt,
                                               deg, pooled);

    // CSR build (by dst)
    deg_kernel<<<N_EDGES / 256, 256, 0, stream>>>(ei, deg);
    scan_kernel<<<1, 256, 0, stream>>>(deg, row_start, pos);
    fill_kernel<<<N_EDGES / 256, 256, 0, stream>>>(ei, pos, col);

    // xlr = x @ [W_l | W_r]  (bf16 MFMA, bf16 out)
    gemm_bt_kernel<<<dim3((2 * HID) / BN, N_NODES / BM), 256, 0, stream>>>(
        xb, bt1, xlr, 2 * HID, IN_DIM);

    // SAGE mean-agg + h + attention scalars
    sage_agg_kernel<<<N_NODES / 4, 256, 0, stream>>>(xlr, row_start, col, sage_b_l, watt, hb, a_att);

    // GAT single-sweep softmax-weighted aggregation
    gat_agg_kernel<<<N_NODES / 4, 256, 0, stream>>>(hb, a_att, row_start, col, T);

    // out_nodes GEMM fused with batch-sum pooling
    gemm_bt_pool_kernel<<<dim3(HID / BN, N_NODES / BM), 256, 0, stream>>>(
        T, bt2, batch, gat_b, 0.25f, pooled, HID, HEADS * HID);

    // mean + action head
    head_kernel<<<NBATCH, 256, 0, stream>>>(pooled, batch, head_w, head_b, out);
}

// Round 6
// 262.356 us; speedup vs baseline: 2.2080x; 1.0001x over previous
//
#include <hip/hip_runtime.h>
#include <math.h>

#define N_NODES 16384
#define N_EDGES 262144
#define IN_DIM  512
#define HID     256
#define HEADS   4
#define NBATCH  64
#define ACTIONS 32
#define NEG_SLOPE 0.2f

typedef __attribute__((ext_vector_type(8))) short short8;
typedef __attribute__((ext_vector_type(4))) float f32x4;

__device__ __forceinline__ float lrelu(float v) { return v > 0.f ? v : NEG_SLOPE * v; }

__device__ __forceinline__ unsigned short bf16_rne(float f) {
    union { float f; unsigned int u; } x; x.f = f;
    unsigned int u = x.u;
    unsigned int r = (u + 0x7FFFu + ((u >> 16) & 1u)) >> 16;
    return (unsigned short)r;
}

__device__ __forceinline__ float bf16_to_f32(unsigned short s) {
    union { unsigned int u; float f; } x; x.u = (unsigned int)s << 16;
    return x.f;
}

__device__ __forceinline__ float4 bf4_to_f4(ushort4 u) {
    return make_float4(bf16_to_f32(u.x), bf16_to_f32(u.y), bf16_to_f32(u.z), bf16_to_f32(u.w));
}

__device__ __forceinline__ void async_copy16(const unsigned short* g, unsigned short* l) {
    __builtin_amdgcn_global_load_lds(
        (const __attribute__((address_space(1))) unsigned int*)g,
        (__attribute__((address_space(3))) unsigned int*)l, 16, 0, 0);
}

// ---------------------------------------------------------------- fused setup
#define NB_CONV 8192
#define NB_WLR  1024
#define NB_WSTK 1024
#define NB_WATT 8
#define NB_ZERO 128
#define NB_SETUP (NB_CONV + NB_WLR + NB_WSTK + NB_WATT + NB_ZERO)

__global__ __launch_bounds__(256) void setup_kernel(
        const float* __restrict__ x, unsigned short* __restrict__ xb,
        const float* __restrict__ wl, const float* __restrict__ wr, unsigned short* __restrict__ bt1,
        const float* __restrict__ gat_w, unsigned short* __restrict__ bt2,
        const float* __restrict__ att_src, const float* __restrict__ att_dst, float* __restrict__ watt,
        int* __restrict__ deg, float* __restrict__ pooled) {
    int bid = blockIdx.x, tid = threadIdx.x;
    if (bid < NB_CONV) {
        int i = (bid * 256 + tid) * 4;
        float4 v = *(const float4*)(x + i);
        ushort4 o;
        o.x = bf16_rne(v.x); o.y = bf16_rne(v.y); o.z = bf16_rne(v.z); o.w = bf16_rne(v.w);
        *(ushort4*)(xb + i) = o;
    } else if (bid < NB_CONV + NB_WLR) {
        int idx = (bid - NB_CONV) * 256 + tid;
        int j = idx >> 9;
        int k = idx & 511;
        float v = (j < HID) ? wl[k * HID + j] : wr[k * HID + (j - HID)];
        bt1[idx] = bf16_rne(v);
    } else if (bid < NB_CONV + NB_WLR + NB_WSTK) {
        int idx = (bid - NB_CONV - NB_WLR) * 256 + tid;
        int c = idx >> 10;
        int r = idx & 1023;
        int h = r >> 8;
        int k = r & 255;
        bt2[idx] = bf16_rne(gat_w[(size_t)k * (HEADS * HID) + h * HID + c]);
    } else if (bid < NB_CONV + NB_WLR + NB_WSTK + NB_WATT) {
        int j = bid - NB_CONV - NB_WLR - NB_WSTK;
        int c = tid;
        int hh = j & 3;
        const float* att = (j < 4) ? (att_src + hh * HID) : (att_dst + hh * HID);
        float s = 0.f;
        for (int cc = 0; cc < HID; cc++)
            s += gat_w[(size_t)c * (HEADS * HID) + hh * HID + cc] * att[cc];
        watt[j * HID + c] = s;
    } else {
        int idx = (bid - NB_CONV - NB_WLR - NB_WSTK - NB_WATT) * 256 + tid;
        if (idx < N_NODES) deg[idx] = 0;
        else pooled[idx - N_NODES] = 0.f;
    }
}

// ---------------------------------------------------------------- CSR build
__global__ void deg_kernel(const int* __restrict__ ei, int* __restrict__ deg) {
    int e = blockIdx.x * 256 + threadIdx.x;
    if (e < N_EDGES) atomicAdd(&deg[ei[N_EDGES + e]], 1);
}

__global__ __launch_bounds__(256) void scan_kernel(const int* __restrict__ deg,
                                                   int* __restrict__ row_start,
                                                   int* __restrict__ pos) {
    int t = threadIdx.x;
    int lane = t & 63, wv = t >> 6;
    int base = t * 64;
    int4 buf[16];
    int sum = 0;
#pragma unroll
    for (int i = 0; i < 16; i++) {
        buf[i] = ((const int4*)(deg + base))[i];
        sum += buf[i].x + buf[i].y + buf[i].z + buf[i].w;
    }
    int v = sum;
#pragma unroll
    for (int off = 1; off < 64; off <<= 1) {
        int u = __shfl_up(v, off);
        if (lane >= off) v += u;
    }
    __shared__ int wsum[4];
    if (lane == 63) wsum[wv] = v;
    __syncthreads();
    int wbase = 0;
    for (int w0 = 0; w0 < wv; w0++) wbase += wsum[w0];
    int run = wbase + v - sum;
#pragma unroll
    for (int i = 0; i < 16; i++) {
        int4 b = buf[i];
        int4 o;
        o.x = run; run += b.x;
        o.y = run; run += b.y;
        o.z = run; run += b.z;
        o.w = run; run += b.w;
        ((int4*)(row_start + base))[i] = o;
        ((int4*)(pos + base))[i] = o;
    }
    if (t == 255) row_start[N_NODES] = run;
}

__global__ void fill_kernel(const int* __restrict__ ei, int* __restrict__ pos,
                            int* __restrict__ col) {
    int e = blockIdx.x * 256 + threadIdx.x;
    if (e < N_EDGES) {
        int s = ei[e];
        int d = ei[N_EDGES + e];
        int p = atomicAdd(&pos[d], 1);
        col[p] = s;
    }
}

// ---------------------------------------------------------------- GEMM1: 64x128 tile, BK=32, 4 blocks/CU
// A [M,K], Bt [N,K] bf16; C bf16.  Waves 2x2: each wave 32 rows x 64 cols.
#define BK 32

__global__ __launch_bounds__(256) void gemm1_kernel(const unsigned short* __restrict__ A,
                                                    const unsigned short* __restrict__ Bt,
                                                    unsigned short* __restrict__ Cb,
                                                    int Nn, int K) {
    __shared__ __align__(16) unsigned short As[64 * BK];    // 4 KB
    __shared__ __align__(16) unsigned short Bs[128 * BK];   // 8 KB

    int tid  = threadIdx.x;
    int wv   = tid >> 6;
    int lane = tid & 63;
    int m0 = blockIdx.y * 64;
    int n0 = blockIdx.x * 128;
    int wm = (wv & 1) * 32;
    int wn = (wv >> 1) * 64;

    int srow = tid >> 2;            // 0..63
    int scol = (tid & 3) * 8;
    const unsigned short* Ag  = A  + (size_t)(m0 + srow) * K + scol;
    const unsigned short* Bg0 = Bt + (size_t)(n0 + srow) * K + scol;
    const unsigned short* Bg1 = Bt + (size_t)(n0 + 64 + srow) * K + scol;
    unsigned short* Al  = As + wv * 512;
    unsigned short* Bl0 = Bs + wv * 512;
    unsigned short* Bl1 = Bs + 2048 + wv * 512;

    int fr = lane & 15;
    int fk = (lane >> 4) * 8;
    f32x4 acc[2][4] = {};

    for (int kt = 0; kt < K; kt += BK) {
        async_copy16(Ag + kt, Al);
        async_copy16(Bg0 + kt, Bl0);
        async_copy16(Bg1 + kt, Bl1);
        __syncthreads();

        short8 af[2], bf[4];
#pragma unroll
        for (int mi = 0; mi < 2; mi++)
            af[mi] = *(const short8*)&As[(wm + mi * 16 + fr) * BK + fk];
#pragma unroll
        for (int ni = 0; ni < 4; ni++)
            bf[ni] = *(const short8*)&Bs[(wn + ni * 16 + fr) * BK + fk];
#pragma unroll
        for (int mi = 0; mi < 2; mi++)
#pragma unroll
            for (int ni = 0; ni < 4; ni++)
                acc[mi][ni] = __builtin_amdgcn_mfma_f32_16x16x32_bf16(af[mi], bf[ni], acc[mi][ni], 0, 0, 0);
        __syncthreads();
    }

    int cr = (lane >> 4) * 4;
    int cc = lane & 15;
#pragma unroll
    for (int mi = 0; mi < 2; mi++) {
#pragma unroll
        for (int ni = 0; ni < 4; ni++) {
            int gc = n0 + wn + ni * 16 + cc;
#pragma unroll
            for (int r = 0; r < 4; r++) {
                int gr = m0 + wm + mi * 16 + cr + r;
                Cb[(size_t)gr * Nn + gc] = bf16_rne(acc[mi][ni][r]);
            }
        }
    }
}

// ---------------------------------------------------------------- GEMM2: 64x64 tile, fused pool atomics
// pooled[batch[m]][n] += relu(A@Bt^T * scale + bias[n])
__global__ __launch_bounds__(256) void gemm2_pool_kernel(const unsigned short* __restrict__ A,
                                                         const unsigned short* __restrict__ Bt,
                                                         const int* __restrict__ batch,
                                                         const float* __restrict__ bias,
                                                         float scale,
                                                         float* __restrict__ pooled,
                                                         int Nn, int K) {
    __shared__ __align__(16) unsigned short As[64 * BK];    // 4 KB
    __shared__ __align__(16) unsigned short Bs[64 * BK];    // 4 KB
    __shared__ int bsh[64];

    int tid  = threadIdx.x;
    int wv   = tid >> 6;
    int lane = tid & 63;
    int m0 = blockIdx.y * 64;
    int n0 = blockIdx.x * 64;
    int wm = (wv & 1) * 32;
    int wn = (wv >> 1) * 32;

    if (tid < 64) bsh[tid] = batch[m0 + tid];

    int srow = tid >> 2;
    int scol = (tid & 3) * 8;
    const unsigned short* Ag = A  + (size_t)(m0 + srow) * K + scol;
    const unsigned short* Bg = Bt + (size_t)(n0 + srow) * K + scol;
    unsigned short* Al = As + wv * 512;
    unsigned short* Bl = Bs + wv * 512;

    int fr = lane & 15;
    int fk = (lane >> 4) * 8;
    f32x4 acc[2][2] = {};

    for (int kt = 0; kt < K; kt += BK) {
        async_copy16(Ag + kt, Al);
        async_copy16(Bg + kt, Bl);
        __syncthreads();

        short8 af[2], bf[2];
#pragma unroll
        for (int mi = 0; mi < 2; mi++)
            af[mi] = *(const short8*)&As[(wm + mi * 16 + fr) * BK + fk];
#pragma unroll
        for (int ni = 0; ni < 2; ni++)
            bf[ni] = *(const short8*)&Bs[(wn + ni * 16 + fr) * BK + fk];
#pragma unroll
        for (int mi = 0; mi < 2; mi++)
#pragma unroll
            for (int ni = 0; ni < 2; ni++)
                acc[mi][ni] = __builtin_amdgcn_mfma_f32_16x16x32_bf16(af[mi], bf[ni], acc[mi][ni], 0, 0, 0);
        __syncthreads();
    }

    int cr = (lane >> 4) * 4;
    int cc = lane & 15;
#pragma unroll
    for (int mi = 0; mi < 2; mi++) {
        int rowb = wm + mi * 16 + cr;
        int b0 = bsh[rowb], b3 = bsh[rowb + 3];
#pragma unroll
        for (int ni = 0; ni < 2; ni++) {
            int gc = n0 + wn + ni * 16 + cc;
            float b = bias[gc];
            float v0 = fmaxf(fmaf(acc[mi][ni][0], scale, b), 0.f);
            float v1 = fmaxf(fmaf(acc[mi][ni][1], scale, b), 0.f);
            float v2 = fmaxf(fmaf(acc[mi][ni][2], scale, b), 0.f);
            float v3 = fmaxf(fmaf(acc[mi][ni][3], scale, b), 0.f);
            if (b0 == b3) {
                atomicAdd(&pooled[b0 * HID + gc], (v0 + v1) + (v2 + v3));
            } else {
                atomicAdd(&pooled[bsh[rowb + 0] * HID + gc], v0);
                atomicAdd(&pooled[bsh[rowb + 1] * HID + gc], v1);
                atomicAdd(&pooled[bsh[rowb + 2] * HID + gc], v2);
                atomicAdd(&pooled[bsh[rowb + 3] * HID + gc], v3);
            }
        }
    }
}

// ---------------------------------------------------------------- SAGE aggregation + h + attention scalars
__global__ __launch_bounds__(256) void sage_agg_kernel(const unsigned short* __restrict__ xlr,
                                                       const int* __restrict__ row_start,
                                                       const int* __restrict__ col,
                                                       const float* __restrict__ b_l,
                                                       const float* __restrict__ watt,
                                                       unsigned short* __restrict__ hb,
                                                       float* __restrict__ a_att) {
    __shared__ float watt_s[8 * HID];
    for (int i = threadIdx.x; i < 8 * HID; i += 256) watt_s[i] = watt[i];
    __syncthreads();

    int wave = threadIdx.x >> 6;
    int lane = threadIdx.x & 63;
    int n = blockIdx.x * 4 + wave;
    int start = row_start[n], end = row_start[n + 1];
    int c0 = lane * 4;

    float4 acc = make_float4(0.f, 0.f, 0.f, 0.f);
    int e = start;
    for (; e + 4 <= end; e += 4) {
        int s0 = col[e], s1 = col[e + 1], s2 = col[e + 2], s3 = col[e + 3];
        ushort4 u0 = *(const ushort4*)(xlr + (size_t)s0 * IN_DIM + c0);
        ushort4 u1 = *(const ushort4*)(xlr + (size_t)s1 * IN_DIM + c0);
        ushort4 u2 = *(const ushort4*)(xlr + (size_t)s2 * IN_DIM + c0);
        ushort4 u3 = *(const ushort4*)(xlr + (size_t)s3 * IN_DIM + c0);
        float4 v0 = bf4_to_f4(u0), v1 = bf4_to_f4(u1), v2 = bf4_to_f4(u2), v3 = bf4_to_f4(u3);
        acc.x += (v0.x + v1.x) + (v2.x + v3.x);
        acc.y += (v0.y + v1.y) + (v2.y + v3.y);
        acc.z += (v0.z + v1.z) + (v2.z + v3.z);
        acc.w += (v0.w + v1.w) + (v2.w + v3.w);
    }
    for (; e < end; e++) {
        int s = col[e];
        float4 v = bf4_to_f4(*(const ushort4*)(xlr + (size_t)s * IN_DIM + c0));
        acc.x += v.x; acc.y += v.y; acc.z += v.z; acc.w += v.w;
    }
    float inv = 1.f / (float)max(end - start, 1);
    float4 xr = bf4_to_f4(*(const ushort4*)(xlr + (size_t)n * IN_DIM + HID + c0));
    float4 bl = *(const float4*)(b_l + c0);
    float4 hv;
    hv.x = fmaxf(fmaf(acc.x, inv, bl.x + xr.x), 0.f);
    hv.y = fmaxf(fmaf(acc.y, inv, bl.y + xr.y), 0.f);
    hv.z = fmaxf(fmaf(acc.z, inv, bl.z + xr.z), 0.f);
    hv.w = fmaxf(fmaf(acc.w, inv, bl.w + xr.w), 0.f);
    ushort4 ho;
    ho.x = bf16_rne(hv.x); ho.y = bf16_rne(hv.y); ho.z = bf16_rne(hv.z); ho.w = bf16_rne(hv.w);
    *(ushort4*)(hb + (size_t)n * HID + c0) = ho;

    float p[8];
#pragma unroll
    for (int j = 0; j < 8; j++) {
        float4 wt = *(const float4*)&watt_s[j * HID + c0];
        p[j] = hv.x * wt.x + hv.y * wt.y + hv.z * wt.z + hv.w * wt.w;
    }
#pragma unroll
    for (int off = 32; off; off >>= 1)
#pragma unroll
        for (int j = 0; j < 8; j++) p[j] += __shfl_down(p[j], off);
    if (lane == 0) {
#pragma unroll
        for (int j = 0; j < 8; j++) a_att[n * 8 + j] = p[j];
    }
}

// ---------------------------------------------------------------- GAT: single-sweep softmax + aggregation
__global__ __launch_bounds__(256) void gat_agg_kernel(const unsigned short* __restrict__ hb,
                                                      const float* __restrict__ a_att,
                                                      const int* __restrict__ row_start,
                                                      const int* __restrict__ col,
                                                      unsigned short* __restrict__ T) {
    __shared__ __align__(16) float w_s[4][64 * 4];
    int wave = threadIdx.x >> 6;
    int lane = threadIdx.x & 63;
    int n = blockIdx.x * 4 + wave;
    int start = row_start[n], end = row_start[n + 1];

    float4 an = *(const float4*)(a_att + n * 8);
    float4 ad = *(const float4*)(a_att + n * 8 + 4);
    float adst[4] = {ad.x, ad.y, ad.z, ad.w};
    float selfl[4] = {lrelu(an.x + ad.x), lrelu(an.y + ad.y), lrelu(an.z + ad.z), lrelu(an.w + ad.w)};
    float m[4], wself[4];
#pragma unroll
    for (int hh = 0; hh < 4; hh++) {
        m[hh] = fmaxf(selfl[hh], 0.f);
        wself[hh] = __expf(selfl[hh] - m[hh]);
    }

    int c0 = lane * 4;
    float4 hn = bf4_to_f4(*(const ushort4*)(hb + (size_t)n * HID + c0));
    float4 acc[4];
#pragma unroll
    for (int hh = 0; hh < 4; hh++)
        acc[hh] = make_float4(wself[hh] * hn.x, wself[hh] * hn.y, wself[hh] * hn.z, wself[hh] * hn.w);

    float dpart[4] = {0.f, 0.f, 0.f, 0.f};

    for (int base = start; base < end; base += 64) {
        int cnt = min(64, end - base);
        if (lane < cnt) {
            int s = col[base + lane];
            float4 as = *(const float4*)(a_att + s * 8);
            float4 wv;
            wv.x = __expf(lrelu(as.x + adst[0]) - m[0]);
            wv.y = __expf(lrelu(as.y + adst[1]) - m[1]);
            wv.z = __expf(lrelu(as.z + adst[2]) - m[2]);
            wv.w = __expf(lrelu(as.w + adst[3]) - m[3]);
            *(float4*)&w_s[wave][lane * 4] = wv;
            dpart[0] += wv.x; dpart[1] += wv.y; dpart[2] += wv.z; dpart[3] += wv.w;
        }
        __builtin_amdgcn_wave_barrier();

        int i = 0;
        for (; i + 2 <= cnt; i += 2) {
            int s0 = col[base + i], s1 = col[base + i + 1];
            float4 w0 = *(const float4*)&w_s[wave][i * 4];
            float4 w1 = *(const float4*)&w_s[wave][(i + 1) * 4];
            ushort4 u0 = *(const ushort4*)(hb + (size_t)s0 * HID + c0);
            ushort4 u1 = *(const ushort4*)(hb + (size_t)s1 * HID + c0);
            float4 h0 = bf4_to_f4(u0), h1 = bf4_to_f4(u1);
            float wr0[4] = {w0.x, w0.y, w0.z, w0.w};
            float wr1[4] = {w1.x, w1.y, w1.z, w1.w};
#pragma unroll
            for (int hh = 0; hh < 4; hh++) {
                acc[hh].x = fmaf(wr0[hh], h0.x, fmaf(wr1[hh], h1.x, acc[hh].x));
                acc[hh].y = fmaf(wr0[hh], h0.y, fmaf(wr1[hh], h1.y, acc[hh].y));
                acc[hh].z = fmaf(wr0[hh], h0.z, fmaf(wr1[hh], h1.z, acc[hh].z));
                acc[hh].w = fmaf(wr0[hh], h0.w, fmaf(wr1[hh], h1.w, acc[hh].w));
            }
        }
        if (i < cnt) {
            int s0 = col[base + i];
            float4 w0 = *(const float4*)&w_s[wave][i * 4];
            float4 h0 = bf4_to_f4(*(const ushort4*)(hb + (size_t)s0 * HID + c0));
            float wr0[4] = {w0.x, w0.y, w0.z, w0.w};
#pragma unroll
            for (int hh = 0; hh < 4; hh++) {
                acc[hh].x = fmaf(wr0[hh], h0.x, acc[hh].x);
                acc[hh].y = fmaf(wr0[hh], h0.y, acc[hh].y);
                acc[hh].z = fmaf(wr0[hh], h0.z, acc[hh].z);
                acc[hh].w = fmaf(wr0[hh], h0.w, acc[hh].w);
            }
        }
        __builtin_amdgcn_wave_barrier();
    }

#pragma unroll
    for (int off = 32; off; off >>= 1)
#pragma unroll
        for (int hh = 0; hh < 4; hh++) dpart[hh] += __shfl_down(dpart[hh], off);
    float invd[4];
#pragma unroll
    for (int hh = 0; hh < 4; hh++)
        invd[hh] = 1.f / (__shfl(dpart[hh], 0) + wself[hh]);

#pragma unroll
    for (int hh = 0; hh < 4; hh++) {
        ushort4 o;
        o.x = bf16_rne(acc[hh].x * invd[hh]); o.y = bf16_rne(acc[hh].y * invd[hh]);
        o.z = bf16_rne(acc[hh].z * invd[hh]); o.w = bf16_rne(acc[hh].w * invd[hh]);
        *(ushort4*)(T + (size_t)n * (HEADS * HID) + hh * HID + c0) = o;
    }
}

// ---------------------------------------------------------------- head
__device__ __forceinline__ int lower_bound_i(const int* a, int n, int v) {
    int lo = 0, hi = n;
    while (lo < hi) {
        int mid = (lo + hi) >> 1;
        if (a[mid] < v) lo = mid + 1; else hi = mid;
    }
    return lo;
}

__global__ __launch_bounds__(256) void head_kernel(const float* __restrict__ pooled,
                                                   const int* __restrict__ batch,
                                                   const float* __restrict__ head_w,
                                                   const float* __restrict__ head_b,
                                                   float* __restrict__ out) {
    __shared__ float sm[HID];
    int b = blockIdx.x;
    int c = threadIdx.x;
    int lo = lower_bound_i(batch, N_NODES, b);
    int hi = lower_bound_i(batch, N_NODES, b + 1);
    int cnt = hi - lo;
    sm[c] = pooled[b * HID + c] / (float)max(cnt, 1);
    __syncthreads();
    if (c < ACTIONS) {
        float acc = head_b[c];
        for (int k = 0; k < HID; k++) acc = fmaf(sm[k], head_w[k * ACTIONS + c], acc);
        out[b * ACTIONS + c] = acc;
    }
}

// ---------------------------------------------------------------- launcher
extern "C" void kernel_launch(void* const* d_in, const int* in_sizes, int n_in,
                              void* d_out, int out_size, void* d_ws, size_t ws_size,
                              hipStream_t stream) {
    const float* x        = (const float*)d_in[0];
    const int*   ei       = (const int*)d_in[1];
    const int*   batch    = (const int*)d_in[2];
    const float* sage_w_l = (const float*)d_in[3];
    const float* sage_b_l = (const float*)d_in[4];
    const float* sage_w_r = (const float*)d_in[5];
    const float* gat_w    = (const float*)d_in[6];
    const float* att_src  = (const float*)d_in[7];
    const float* att_dst  = (const float*)d_in[8];
    const float* gat_b    = (const float*)d_in[9];
    const float* head_w   = (const float*)d_in[10];
    const float* head_b   = (const float*)d_in[11];
    float* out = (float*)d_out;

    char* w = (char*)d_ws;
    float* a_att  = (float*)w; w += (size_t)N_NODES * 8 * 4;
    float* watt   = (float*)w; w += (size_t)8 * HID * 4;
    float* pooled = (float*)w; w += (size_t)NBATCH * HID * 4;
    unsigned short* xb  = (unsigned short*)w; w += (size_t)N_NODES * IN_DIM * 2;
    unsigned short* xlr = (unsigned short*)w; w += (size_t)N_NODES * IN_DIM * 2;
    unsigned short* hb  = (unsigned short*)w; w += (size_t)N_NODES * HID * 2;
    unsigned short* T   = (unsigned short*)w; w += (size_t)N_NODES * HEADS * HID * 2;
    unsigned short* bt1 = (unsigned short*)w; w += (size_t)(2 * HID) * IN_DIM * 2;
    unsigned short* bt2 = (unsigned short*)w; w += (size_t)HID * (HEADS * HID) * 2;
    int* deg      = (int*)w;   w += (size_t)N_NODES * 4;
    int* row_start= (int*)w;   w += (size_t)(N_NODES + 64) * 4;
    int* pos      = (int*)w;   w += (size_t)N_NODES * 4;
    int* col      = (int*)w;   w += (size_t)N_EDGES * 4;

    setup_kernel<<<NB_SETUP, 256, 0, stream>>>(x, xb, sage_w_l, sage_w_r, bt1,
                                               gat_w, bt2, att_src, att_dst, watt,
                                               deg, pooled);

    deg_kernel<<<N_EDGES / 256, 256, 0, stream>>>(ei, deg);
    scan_kernel<<<1, 256, 0, stream>>>(deg, row_start, pos);
    fill_kernel<<<N_EDGES / 256, 256, 0, stream>>>(ei, pos, col);

    // xlr = x @ [W_l | W_r]  (64x128 tile -> 1024 blocks, 4/CU)
    gemm1_kernel<<<dim3((2 * HID) / 128, N_NODES / 64), 256, 0, stream>>>(
        xb, bt1, xlr, 2 * HID, IN_DIM);

    sage_agg_kernel<<<N_NODES / 4, 256, 0, stream>>>(xlr, row_start, col, sage_b_l, watt, hb, a_att);

    gat_agg_kernel<<<N_NODES / 4, 256, 0, stream>>>(hb, a_att, row_start, col, T);

    // out_nodes GEMM fused with pooling  (64x64 tile -> 1024 blocks, 4/CU)
    gemm2_pool_kernel<<<dim3(HID / 64, N_NODES / 64), 256, 0, stream>>>(
        T, bt2, batch, gat_b, 0.25f, pooled, HID, HEADS * HID);

    head_kernel<<<NBATCH, 256, 0, stream>>>(pooled, batch, head_w, head_b, out);
}